// Round 2
// baseline (917.002 us; speedup 1.0000x reference)
//
#include <hip/hip_runtime.h>
#include <hip/hip_bf16.h>

#define N_  32
#define C_  64
#define T_  300
#define V_  25
#define TV  (T_*V_)        // 7500
#define CTV (C_*TV)        // 480000
#define NELEM (N_*CTV)     // 15360000
#define CNT 240000         // N*T*V per-channel count

// ---------------------------------------------------------------------------
// Kernel 1: fused 1x1 conv + graph contraction -> g, plus per-channel stats
// grid (T, N), block 256.  LDS: xs[64][25], aeff[5][25][25], zs[320][25], colsum[5][25]
// g[n,c,t,w] = sum_j W'[c,j] * z[j,w] + sum_k conv_b[k*64+c]*colsum[k,w]
//   z[j=k*64+c',w] = sum_v x[n,c',t,v] * aeff[k,v,w]
//   aeff[k] = A[k] (k<3) or lamda*B[n,k-3] (k>=3)
// ---------------------------------------------------------------------------
__global__ __launch_bounds__(256) void k_gcn(
    const float* __restrict__ x, const float* __restrict__ A,
    const float* __restrict__ B, const float* __restrict__ lamda,
    const float* __restrict__ conv_w, const float* __restrict__ conv_b,
    float* __restrict__ g, float* __restrict__ stats)
{
    __shared__ float xs[1600];      // [c'][v]
    __shared__ float aeff[3125];    // [k][v][w]
    __shared__ float zs[8000];      // [k*64+c'][w]
    __shared__ float colsum[125];   // [k][w]

    const int t = blockIdx.x, n = blockIdx.y;
    const int tid = threadIdx.x;
    const float lam = lamda[0];

    for (int e = tid; e < 1600; e += 256) {
        int cp = e / 25, v = e % 25;
        xs[e] = x[n*CTV + cp*TV + t*V_ + v];
    }
    for (int e = tid; e < 3125; e += 256) {
        int k = e / 625, r = e % 625;
        aeff[e] = (k < 3) ? A[e] : lam * B[(n*2 + (k-3))*625 + r];
    }
    __syncthreads();

    for (int e = tid; e < 125; e += 256) {
        int k = e / 25, w = e % 25;
        float s = 0.f;
        #pragma unroll
        for (int v = 0; v < 25; ++v) s += aeff[k*625 + v*25 + w];
        colsum[e] = s;
    }
    for (int idx = tid; idx < 8000; idx += 256) {
        int k = idx / 1600, r = idx % 1600;
        int cp = r / 25, w = r % 25;
        const float* ae = &aeff[k*625 + w];
        const float* xr = &xs[cp*25];
        float s = 0.f;
        #pragma unroll
        for (int v = 0; v < 25; ++v) s = fmaf(xr[v], ae[v*25], s);
        zs[idx] = s;
    }
    __syncthreads();

    // each thread: output channel c = tid>>2, w = q + 4*jw
    const int c = tid >> 2, q = tid & 3;
    float b5[5];
    #pragma unroll
    for (int k = 0; k < 5; ++k) b5[k] = conv_b[k*64 + c];

    float acc[7];
    #pragma unroll
    for (int jw = 0; jw < 7; ++jw) {
        int w = q + 4*jw; int wc = w < 25 ? w : 24;
        float s = 0.f;
        #pragma unroll
        for (int k = 0; k < 5; ++k) s = fmaf(b5[k], colsum[k*25 + wc], s);
        acc[jw] = s;
    }
    for (int j = 0; j < 320; ++j) {
        float wv = conv_w[((j >> 6) << 12) + (c << 6) + (j & 63)];
        const float* zr = &zs[j*25];
        #pragma unroll
        for (int jw = 0; jw < 7; ++jw) {
            int w = q + 4*jw; int wc = w < 25 ? w : 24;
            acc[jw] = fmaf(wv, zr[wc], acc[jw]);
        }
    }

    float lsum = 0.f, lsq = 0.f;
    #pragma unroll
    for (int jw = 0; jw < 7; ++jw) {
        int w = q + 4*jw;
        if (w < 25) {
            float v = acc[jw];
            g[n*CTV + c*TV + t*V_ + w] = v;
            lsum += v;
            lsq = fmaf(v, v, lsq);
        }
    }
    lsum += __shfl_xor(lsum, 1); lsum += __shfl_xor(lsum, 2);
    lsq  += __shfl_xor(lsq, 1);  lsq  += __shfl_xor(lsq, 2);
    if (q == 0) {
        atomicAdd(&stats[c], lsum);
        atomicAdd(&stats[64 + c], lsq);
    }
}

// ---------------------------------------------------------------------------
// Kernel 2/4: finalize BN params.  stats: [which*128 + {0:sum,64:sumsq}]
// sb: [which*128 + {0:scale,64:shift}]
// ---------------------------------------------------------------------------
__global__ void k_fin(const float* __restrict__ stats, float* __restrict__ sb,
                      const float* __restrict__ gma, const float* __restrict__ bta,
                      int which)
{
    int c = threadIdx.x;
    const float invcnt = 1.f / (float)CNT;
    float mean = stats[which*128 + c] * invcnt;
    float var  = stats[which*128 + 64 + c] * invcnt - mean*mean;
    float s = gma[c] * rsqrtf(var + 1e-5f);
    sb[which*128 + c] = s;
    sb[which*128 + 64 + c] = bta[c] - mean*s;
}

// ---------------------------------------------------------------------------
// Kernel 3: temporal conv on relu(bn1(g)) -> h, plus h stats
// grid (ceil(300/8)=38, N), block 256. 16-channel chunks staged in LDS.
// ---------------------------------------------------------------------------
__global__ __launch_bounds__(256) void k_tcn(
    const float* __restrict__ g, const float* __restrict__ sb,
    const float* __restrict__ tw, const float* __restrict__ tb,
    float* __restrict__ h, float* __restrict__ stats)
{
    __shared__ float p[16*16*25];   // [t' 16][ii 16][w 25]

    const int n = blockIdx.y, t0 = blockIdx.x * 8;
    const int tid = threadIdx.x;
    const int c = tid >> 2, q = tid & 3;

    float acc[7][8];
    #pragma unroll
    for (int jw = 0; jw < 7; ++jw)
        #pragma unroll
        for (int to = 0; to < 8; ++to) acc[jw][to] = 0.f;

    for (int ic = 0; ic < 4; ++ic) {
        __syncthreads();
        for (int e = tid; e < 6400; e += 256) {
            int tp = e / 400, r = e % 400, ii = r / 25, w = r % 25;
            int i = ic*16 + ii;
            int gt = t0 - 4 + tp;
            float val = 0.f;
            if (gt >= 0 && gt < T_) {
                float gv = g[n*CTV + i*TV + gt*V_ + w];
                val = fmaxf(fmaf(gv, sb[i], sb[64 + i]), 0.f);
            }
            p[e] = val;
        }
        __syncthreads();

        for (int ii = 0; ii < 16; ++ii) {
            int i = ic*16 + ii;
            float wt[9];
            #pragma unroll
            for (int dt = 0; dt < 9; ++dt) wt[dt] = tw[(c*64 + i)*9 + dt];
            #pragma unroll
            for (int jw = 0; jw < 7; ++jw) {
                int w = q + 4*jw; int wc = w < 25 ? w : 24;
                #pragma unroll
                for (int tp = 0; tp < 16; ++tp) {
                    float pv = p[tp*400 + ii*25 + wc];
                    #pragma unroll
                    for (int dt = 0; dt < 9; ++dt) {
                        int to = tp - dt;   // output tile index
                        if (to >= 0 && to < 8)
                            acc[jw][to] = fmaf(wt[dt], pv, acc[jw][to]);
                    }
                }
            }
        }
    }

    const float bias = tb[c];
    float lsum = 0.f, lsq = 0.f;
    #pragma unroll
    for (int jw = 0; jw < 7; ++jw) {
        int w = q + 4*jw;
        if (w < 25) {
            #pragma unroll
            for (int to = 0; to < 8; ++to) {
                int t = t0 + to;
                if (t < T_) {
                    float v = acc[jw][to] + bias;
                    h[n*CTV + c*TV + t*V_ + w] = v;
                    lsum += v;
                    lsq = fmaf(v, v, lsq);
                }
            }
        }
    }
    lsum += __shfl_xor(lsum, 1); lsum += __shfl_xor(lsum, 2);
    lsq  += __shfl_xor(lsq, 1);  lsq  += __shfl_xor(lsq, 2);
    if (q == 0) {
        atomicAdd(&stats[128 + c], lsum);
        atomicAdd(&stats[192 + c], lsq);
    }
}

// ---------------------------------------------------------------------------
// Kernel 5: out = relu(bn2(h) + x) as FLOAT32 (reference output dtype),
// float4 in / float4 out
// ---------------------------------------------------------------------------
__global__ __launch_bounds__(256) void k_out(
    const float* __restrict__ h, const float* __restrict__ x,
    const float* __restrict__ sb, float* __restrict__ out)
{
    int i4 = blockIdx.x * 256 + threadIdx.x;
    if (i4 >= NELEM/4) return;
    int e = i4 * 4;
    int c = (e / TV) & 63;               // 7500 % 4 == 0 -> channel uniform per float4
    float s2 = sb[128 + c], b2 = sb[192 + c];
    float4 hv = ((const float4*)h)[i4];
    float4 xv = ((const float4*)x)[i4];
    float4 o;
    o.x = fmaxf(fmaf(hv.x, s2, b2) + xv.x, 0.f);
    o.y = fmaxf(fmaf(hv.y, s2, b2) + xv.y, 0.f);
    o.z = fmaxf(fmaf(hv.z, s2, b2) + xv.z, 0.f);
    o.w = fmaxf(fmaf(hv.w, s2, b2) + xv.w, 0.f);
    ((float4*)out)[i4] = o;
}

// ---------------------------------------------------------------------------
extern "C" void kernel_launch(void* const* d_in, const int* in_sizes, int n_in,
                              void* d_out, int out_size, void* d_ws, size_t ws_size,
                              hipStream_t stream)
{
    const float* x      = (const float*)d_in[0];
    const float* A      = (const float*)d_in[1];
    const float* B      = (const float*)d_in[2];
    const float* lamda  = (const float*)d_in[3];
    const float* conv_w = (const float*)d_in[4];
    const float* conv_b = (const float*)d_in[5];
    const float* bn1_g  = (const float*)d_in[6];
    const float* bn1_b  = (const float*)d_in[7];
    const float* tcn_w  = (const float*)d_in[8];
    const float* tcn_b  = (const float*)d_in[9];
    const float* bn2_g  = (const float*)d_in[10];
    const float* bn2_b  = (const float*)d_in[11];

    float* ws    = (float*)d_ws;
    float* g     = ws;                      // 15,360,000 floats
    float* h     = ws + NELEM;              // 15,360,000 floats
    float* stats = ws + 2*NELEM;            // 256 floats
    float* sb    = ws + 2*NELEM + 256;      // 256 floats

    hipMemsetAsync(stats, 0, 256*sizeof(float), stream);

    k_gcn<<<dim3(T_, N_), 256, 0, stream>>>(x, A, B, lamda, conv_w, conv_b, g, stats);
    k_fin<<<1, 64, 0, stream>>>(stats, sb, bn1_g, bn1_b, 0);
    k_tcn<<<dim3((T_ + 7)/8, N_), 256, 0, stream>>>(g, sb, tcn_w, tcn_b, h, stats);
    k_fin<<<1, 64, 0, stream>>>(stats, sb, bn2_g, bn2_b, 1);
    k_out<<<NELEM/4/256, 256, 0, stream>>>(h, x, sb, (unsigned short*)d_out ? (float*)d_out : (float*)d_out);
}

// Round 3
// 346.312 us; speedup vs baseline: 2.6479x; 2.6479x over previous
//
#include <hip/hip_runtime.h>
#include <hip/hip_bf16.h>

#define N_  32
#define C_  64
#define T_  300
#define V_  25
#define TV  (T_*V_)        // 7500
#define CTV (C_*TV)        // 480000
#define NELEM (N_*CTV)     // 15360000
#define CNTF 240000.0f

typedef float f32x4 __attribute__((ext_vector_type(4)));
typedef short bf16x8 __attribute__((ext_vector_type(8)));
typedef short s4v __attribute__((ext_vector_type(4)));
typedef short s8v __attribute__((ext_vector_type(8)));

__device__ __forceinline__ unsigned short f2bf(float f) {
    unsigned u = __float_as_uint(f);
    unsigned r = u + 0x7fffu + ((u >> 16) & 1u);
    return (unsigned short)(r >> 16);
}
__device__ __forceinline__ float bf2f(unsigned short u) {
    return __uint_as_float(((unsigned)u) << 16);
}

// ---------------------------------------------------------------------------
// k_gcn: per (t,n): z[j=k*64+c',w] = sum_v x[c',v]*aeff[k,v,w]  (MFMA, K=32)
//        g[c,w]   = sum_j W2[c,j]*z[j,w] + bias-term            (MFMA, K=320)
// writes g bf16 [n][t][w][c]; per-block BN1 partial stats (deterministic).
// MFMA layouts (m97-verified): A[m=l&15][k=8*(l>>4)+i], B[k=8*(l>>4)+i][n=l&15],
// D[row=4*(l>>4)+r][col=l&15].
// ---------------------------------------------------------------------------
__global__ __launch_bounds__(256) void k_gcn(
    const float* __restrict__ x, const float* __restrict__ A,
    const float* __restrict__ B, const float* __restrict__ lamda,
    const float* __restrict__ conv_w, const float* __restrict__ conv_b,
    unsigned short* __restrict__ gout, float* __restrict__ stats3)
{
    __shared__ unsigned short ash[5*32*40];   // [k][w][v] = aeff[k][v][w], pads zero
    __shared__ unsigned short zsh[32*328];    // [w][j], j<320 used
    __shared__ float csum[5*32];              // colsum[k][w]
    __shared__ float sbc[320];                // conv_b

    const int t = blockIdx.x, n = blockIdx.y;
    const int tid = threadIdx.x;
    const int lane = tid & 63, wv = tid >> 6;
    const int lg = lane >> 4, lr = lane & 15;
    const int crow = lr + 16*wv;              // A-row for both steps

    // ---- A-frag for step 1: x[n][crow][t][v], v = 8*lg + i (zero v>=25)
    const float* xrow = x + n*CTV + crow*TV + t*V_;
    bf16x8 xfrag;
    #pragma unroll
    for (int i = 0; i < 8; ++i) {
        int v = 8*lg + i;
        xfrag[i] = (short)f2bf(v < 25 ? xrow[v] : 0.f);
    }

    // ---- A-frags for step 2: W2[c][j] = conv_w[(j>>6)*64 + c][j&63]
    bf16x8 wfrag[10];
    #pragma unroll
    for (int ks = 0; ks < 10; ++ks) {
        const float* wp = conv_w + (((ks>>1)*64 + crow)*64 + (ks&1)*32 + 8*lg);
        float4 w0 = *(const float4*)wp;
        float4 w1 = *(const float4*)(wp + 4);
        bf16x8 f;
        f[0]=(short)f2bf(w0.x); f[1]=(short)f2bf(w0.y); f[2]=(short)f2bf(w0.z); f[3]=(short)f2bf(w0.w);
        f[4]=(short)f2bf(w1.x); f[5]=(short)f2bf(w1.y); f[6]=(short)f2bf(w1.z); f[7]=(short)f2bf(w1.w);
        wfrag[ks] = f;
    }

    // ---- stage aeff^T (bf16) and conv_b
    const float lam = lamda[0];
    for (int e = tid; e < 6400; e += 256) {
        int k = e / 1280, r = e % 1280, w = r / 40, v = r % 40;
        float val = 0.f;
        if (w < 25 && v < 25)
            val = (k < 3) ? A[k*625 + v*25 + w]
                          : lam * B[((n<<1) + (k-3))*625 + v*25 + w];
        ash[e] = f2bf(val);
    }
    for (int e = tid; e < 320; e += 256) sbc[e] = conv_b[e];
    __syncthreads();

    // colsum[k][w] (for the conv-bias-through-adjacency term)
    for (int e = tid; e < 160; e += 256) {
        int k = e / 32, w = e % 32;
        float s = 0.f;
        for (int v = 0; v < 25; ++v) s += bf2f(ash[k*1280 + w*40 + v]);
        csum[e] = s;
    }

    // ---- step 1: z tiles -> zsh[w][j] bf16
    #pragma unroll
    for (int k = 0; k < 5; ++k) {
        #pragma unroll
        for (int nt = 0; nt < 2; ++nt) {
            bf16x8 bfrag = *(const bf16x8*)&ash[k*1280 + (lr + 16*nt)*40 + 8*lg];
            f32x4 z = {0.f,0.f,0.f,0.f};
            z = __builtin_amdgcn_mfma_f32_16x16x32_bf16(xfrag, bfrag, z, 0, 0, 0);
            s4v z4;
            #pragma unroll
            for (int r = 0; r < 4; ++r) z4[r] = (short)f2bf(z[r]);
            *(s4v*)&zsh[(lr + 16*nt)*328 + k*64 + 16*wv + 4*lg] = z4;
        }
    }
    __syncthreads();

    // ---- step 2: g = W2 * z  (K=320)
    f32x4 acc0 = {0.f,0.f,0.f,0.f}, acc1 = {0.f,0.f,0.f,0.f};
    #pragma unroll
    for (int ks = 0; ks < 10; ++ks) {
        bf16x8 b0 = *(const bf16x8*)&zsh[lr*328 + 32*ks + 8*lg];
        bf16x8 b1 = *(const bf16x8*)&zsh[(lr+16)*328 + 32*ks + 8*lg];
        acc0 = __builtin_amdgcn_mfma_f32_16x16x32_bf16(wfrag[ks], b0, acc0, 0, 0, 0);
        acc1 = __builtin_amdgcn_mfma_f32_16x16x32_bf16(wfrag[ks], b1, acc1, 0, 0, 0);
    }

    // ---- epilogue: bias, write g (bf16 [n][t][w][c]), block stats
    const int cbase = 16*wv + 4*lg;
    unsigned short* grow = gout + (size_t)(n*300 + t)*1600;  // 25*64
    float v0a[4], v1a[4];
    #pragma unroll
    for (int r = 0; r < 4; ++r) {
        int c = cbase + r;
        float bs0 = 0.f, bs1 = 0.f;
        #pragma unroll
        for (int k = 0; k < 5; ++k) {
            float cb = sbc[k*64 + c];
            bs0 += cb * csum[k*32 + lr];
            bs1 += cb * csum[k*32 + lr + 16];
        }
        v0a[r] = acc0[r] + bs0;
        v1a[r] = acc1[r] + bs1;
    }
    s4v g0, g1;
    #pragma unroll
    for (int r = 0; r < 4; ++r) { g0[r] = (short)f2bf(v0a[r]); g1[r] = (short)f2bf(v1a[r]); }
    *(s4v*)&grow[lr*64 + cbase] = g0;
    if (lr < 9) *(s4v*)&grow[(lr+16)*64 + cbase] = g1;

    const int bidx = n*300 + t;
    #pragma unroll
    for (int r = 0; r < 4; ++r) {
        float sv = v0a[r] + (lr < 9 ? v1a[r] : 0.f);
        float qv = v0a[r]*v0a[r] + (lr < 9 ? v1a[r]*v1a[r] : 0.f);
        sv += __shfl_xor(sv, 1); sv += __shfl_xor(sv, 2);
        sv += __shfl_xor(sv, 4); sv += __shfl_xor(sv, 8);
        qv += __shfl_xor(qv, 1); qv += __shfl_xor(qv, 2);
        qv += __shfl_xor(qv, 4); qv += __shfl_xor(qv, 8);
        if (lr == 0) {
            stats3[bidx*128 + cbase + r] = sv;
            stats3[bidx*128 + 64 + cbase + r] = qv;
        }
    }
}

// ---------------------------------------------------------------------------
// k_fin: reduce per-block stats -> BN scale/shift. grid 64 (one block per c).
// ---------------------------------------------------------------------------
__global__ __launch_bounds__(256) void k_fin(
    const float* __restrict__ src, int count, float* __restrict__ sbo,
    const float* __restrict__ gma, const float* __restrict__ bta)
{
    const int c = blockIdx.x, tid = threadIdx.x;
    float s = 0.f, q = 0.f;
    for (int b = tid; b < count; b += 256) {
        s += src[b*128 + c];
        q += src[b*128 + 64 + c];
    }
    #pragma unroll
    for (int m = 1; m < 64; m <<= 1) { s += __shfl_xor(s, m); q += __shfl_xor(q, m); }
    __shared__ float rs[4], rq[4];
    if ((tid & 63) == 0) { rs[tid>>6] = s; rq[tid>>6] = q; }
    __syncthreads();
    if (tid == 0) {
        s = rs[0]+rs[1]+rs[2]+rs[3]; q = rq[0]+rq[1]+rq[2]+rq[3];
        float mean = s / CNTF, var = q / CNTF - mean*mean;
        float sc = gma[c] * rsqrtf(var + 1e-5f);
        sbo[c] = sc;
        sbo[64 + c] = bta[c] - mean*sc;
    }
}

// ---------------------------------------------------------------------------
// k_tcn: h[c,t,w] = sum_dt sum_i tw[c,i,dt]*relu(bn1(g))[i,t+dt-4,w] + tb[c]
// grid (38, N). pT[16 tau][25 w][72 i] bf16; 9 dt x 2 ks MFMA; LDS-transpose
// epilogue -> h bf16 [n][c][t][w] + block stats.
// ---------------------------------------------------------------------------
__global__ __launch_bounds__(256) void k_tcn(
    const unsigned short* __restrict__ gin, const float* __restrict__ sb,
    const float* __restrict__ tw, const float* __restrict__ tb,
    unsigned short* __restrict__ hout, float* __restrict__ stats4)
{
    __shared__ unsigned short pT[16*25*72];   // 57600 B (reused as hbuf f32 later)
    __shared__ float sbs[128];

    const int n = blockIdx.y, tt = blockIdx.x, t0 = tt*8;
    const int tid = threadIdx.x;
    const int lane = tid & 63, wv = tid >> 6;
    const int lg = lane >> 4, lr = lane & 15;
    const int c = lr + 16*wv;

    // A-frags: tw[c][i][dt], i = 32ks+8lg+ii
    bf16x8 af[18];
    #pragma unroll
    for (int dt = 0; dt < 9; ++dt)
        #pragma unroll
        for (int ks = 0; ks < 2; ++ks) {
            bf16x8 f;
            #pragma unroll
            for (int ii = 0; ii < 8; ++ii) {
                int i = 32*ks + 8*lg + ii;
                f[ii] = (short)f2bf(tw[(c*64 + i)*9 + dt]);
            }
            af[dt*2 + ks] = f;
        }

    for (int e = tid; e < 128; e += 256) sbs[e] = sb[e];
    __syncthreads();

    // stage p = relu(bn1(g)) into pT[tl][w][i]
    for (int e8 = tid; e8 < 3200; e8 += 256) {
        int tl = e8 / 200, r = e8 % 200, w = r >> 3, i8 = (r & 7) * 8;
        int tg = t0 - 4 + tl;
        s8v val8 = {0,0,0,0,0,0,0,0};
        if (tg >= 0 && tg < 300) {
            s8v raw = *(const s8v*)&gin[(size_t)((n*300 + tg)*25 + w)*64 + i8];
            #pragma unroll
            for (int j = 0; j < 8; ++j) {
                float f = fmaf(bf2f((unsigned short)raw[j]), sbs[i8+j], sbs[64+i8+j]);
                val8[j] = (short)f2bf(fmaxf(f, 0.f));
            }
        }
        *(s8v*)&pT[(tl*25 + w)*72 + i8] = val8;
    }
    __syncthreads();

    // MFMA: 13 N-tiles of 16 cols (col = tl*25+w), K = 64 i x 9 dt
    f32x4 acc[13];
    #pragma unroll
    for (int nt = 0; nt < 13; ++nt) {
        int col = lr + 16*nt; if (col > 199) col = 199;
        int tlo = (col*41) >> 10;          // col/25 for col<1024
        int w = col - tlo*25;
        f32x4 a = {0.f,0.f,0.f,0.f};
        #pragma unroll
        for (int dt = 0; dt < 9; ++dt) {
            int rowbase = ((tlo + dt)*25 + w)*72 + 8*lg;
            bf16x8 b0 = *(const bf16x8*)&pT[rowbase];
            bf16x8 b1 = *(const bf16x8*)&pT[rowbase + 32];
            a = __builtin_amdgcn_mfma_f32_16x16x32_bf16(af[dt*2],     b0, a, 0, 0, 0);
            a = __builtin_amdgcn_mfma_f32_16x16x32_bf16(af[dt*2 + 1], b1, a, 0, 0, 0);
        }
        acc[nt] = a;
    }
    __syncthreads();

    // transpose via LDS: hbuf[c][tl][w] f32 (51200 B <= 57600)
    float* hbuf = (float*)pT;
    const int cbase = 16*wv + 4*lg;
    float tbc[4];
    #pragma unroll
    for (int r = 0; r < 4; ++r) tbc[r] = tb[cbase + r];
    #pragma unroll
    for (int nt = 0; nt < 13; ++nt) {
        int col = lr + 16*nt;
        if (col < 200) {
            #pragma unroll
            for (int r = 0; r < 4; ++r)
                hbuf[(cbase + r)*200 + col] = acc[nt][r] + tbc[r];
        }
    }
    __syncthreads();

    // coalesced write h bf16 [n][c][t][w] + stats
    const int oc = tid >> 2, part = tid & 3;
    const int lim = min(200, (300 - t0)*25);
    const float* hrow = hbuf + oc*200 + part*50;
    unsigned short* hg = hout + ((size_t)(n*64 + oc)*300 + t0)*25 + part*50;
    float s = 0.f, q = 0.f;
    for (int m = 0; m < 50; ++m) {
        int gm = part*50 + m;
        if (gm < lim) {
            float v = hrow[m];
            s += v; q = fmaf(v, v, q);
            hg[m] = f2bf(v);
        }
    }
    s += __shfl_xor(s, 1); s += __shfl_xor(s, 2);
    q += __shfl_xor(q, 1); q += __shfl_xor(q, 2);
    if (part == 0) {
        stats4[(n*38 + tt)*128 + oc] = s;
        stats4[(n*38 + tt)*128 + 64 + oc] = q;
    }
}

// ---------------------------------------------------------------------------
// k_out: out = relu(bn2(h) + x)  f32, h bf16 [n][c][t][w] matches x layout
// ---------------------------------------------------------------------------
__global__ __launch_bounds__(256) void k_out(
    const unsigned short* __restrict__ h, const float* __restrict__ x,
    const float* __restrict__ sb, float* __restrict__ out)
{
    int i4 = blockIdx.x * 256 + threadIdx.x;
    if (i4 >= NELEM/4) return;
    int c = ((i4*4) / TV) & 63;
    float s2 = sb[128 + c], b2 = sb[192 + c];
    s4v hv = *(const s4v*)&h[i4*4];
    float4 xv = ((const float4*)x)[i4];
    float4 o;
    o.x = fmaxf(fmaf(bf2f((unsigned short)hv[0]), s2, b2) + xv.x, 0.f);
    o.y = fmaxf(fmaf(bf2f((unsigned short)hv[1]), s2, b2) + xv.y, 0.f);
    o.z = fmaxf(fmaf(bf2f((unsigned short)hv[2]), s2, b2) + xv.z, 0.f);
    o.w = fmaxf(fmaf(bf2f((unsigned short)hv[3]), s2, b2) + xv.w, 0.f);
    ((float4*)out)[i4] = o;
}

// ---------------------------------------------------------------------------
extern "C" void kernel_launch(void* const* d_in, const int* in_sizes, int n_in,
                              void* d_out, int out_size, void* d_ws, size_t ws_size,
                              hipStream_t stream)
{
    const float* x      = (const float*)d_in[0];
    const float* A      = (const float*)d_in[1];
    const float* B      = (const float*)d_in[2];
    const float* lamda  = (const float*)d_in[3];
    const float* conv_w = (const float*)d_in[4];
    const float* conv_b = (const float*)d_in[5];
    const float* bn1_g  = (const float*)d_in[6];
    const float* bn1_b  = (const float*)d_in[7];
    const float* tcn_w  = (const float*)d_in[8];
    const float* tcn_b  = (const float*)d_in[9];
    const float* bn2_g  = (const float*)d_in[10];
    const float* bn2_b  = (const float*)d_in[11];

    unsigned short* g = (unsigned short*)d_ws;          // 15.36M bf16
    unsigned short* h = g + NELEM;                      // 15.36M bf16
    float* stats3 = (float*)(h + NELEM);                // 9600*128
    float* stats4 = stats3 + 9600*128;                  // 1216*128
    float* sb     = stats4 + 1216*128;                  // 256

    k_gcn<<<dim3(T_, N_), 256, 0, stream>>>(x, A, B, lamda, conv_w, conv_b, g, stats3);
    k_fin<<<64, 256, 0, stream>>>(stats3, 9600, sb, bn1_g, bn1_b);
    k_tcn<<<dim3(38, N_), 256, 0, stream>>>(g, sb, tcn_w, tcn_b, h, stats4);
    k_fin<<<64, 256, 0, stream>>>(stats4, 1216, sb + 128, bn2_g, bn2_b);
    k_out<<<NELEM/4/256, 256, 0, stream>>>(h, x, sb, (float*)d_out);
}

// Round 4
// 144.798 us; speedup vs baseline: 6.3330x; 2.3917x over previous
//
#include <hip/hip_runtime.h>
#include <hip/hip_bf16.h>

#define N_  32
#define C_  64
#define T_  300
#define V_  25
#define TV  (T_*V_)        // 7500
#define CTV (C_*TV)        // 480000
#define NELEM (N_*CTV)     // 15360000
#define CNTF 240000.0f

typedef float f32x4 __attribute__((ext_vector_type(4)));
typedef short bf16x8 __attribute__((ext_vector_type(8)));
typedef short s4v __attribute__((ext_vector_type(4)));
typedef short s8v __attribute__((ext_vector_type(8)));

__device__ __forceinline__ unsigned short f2bf(float f) {
    unsigned u = __float_as_uint(f);
    unsigned r = u + 0x7fffu + ((u >> 16) & 1u);
    return (unsigned short)(r >> 16);
}
__device__ __forceinline__ float bf2f(unsigned short u) {
    return __uint_as_float(((unsigned)u) << 16);
}

// ---------------------------------------------------------------------------
// k_prep: one-time weight conversion to bf16 in MFMA A-frag friendly layouts.
// w2b[(ks*64+c)*32+kk] = conv_w[((ks>>1)*64+c)*64 + (ks&1)*32+kk]   (20480)
// twb[((dt*2+ks)*64+c)*32+kk] = tcn_w[(c*64 + 32*ks+kk)*9 + dt]     (36864)
// ---------------------------------------------------------------------------
__global__ __launch_bounds__(256) void k_prep(
    const float* __restrict__ conv_w, const float* __restrict__ tw,
    unsigned short* __restrict__ w2b, unsigned short* __restrict__ twb)
{
    int tid = blockIdx.x*256 + threadIdx.x;
    for (int e = tid; e < 20480; e += 8192) {
        int ks = e >> 11, c = (e >> 5) & 63, kk = e & 31;
        w2b[e] = f2bf(conv_w[(((ks>>1)*64 + c)*64) + (ks&1)*32 + kk]);
    }
    for (int e = tid; e < 36864; e += 8192) {
        int gi = e >> 11, c = (e >> 5) & 63, kk = e & 31;
        int dt = gi >> 1, ks = gi & 1;
        twb[e] = f2bf(tw[(c*64 + 32*ks + kk)*9 + dt]);
    }
}

// ---------------------------------------------------------------------------
// k_gcn: grid (30, 32), 10 t per block. Per t:
//   z[j,w] = sum_v x[c',v]*aeff[k,v,w] (MFMA K=32), zsh transpose,
//   g[c,w] = W2[c,:] @ z[:,w] (MFMA K=320) + bias-term.
// aeff/csum/wfrag/bias-sums hoisted; stats in regs; coalesced g write via gsh.
// ---------------------------------------------------------------------------
__global__ __launch_bounds__(256) void k_gcn(
    const float* __restrict__ x, const float* __restrict__ A,
    const float* __restrict__ B, const float* __restrict__ lamda,
    const unsigned short* __restrict__ w2b, const float* __restrict__ conv_b,
    unsigned short* __restrict__ gout, float* __restrict__ stats3)
{
    __shared__ unsigned short ash[5*32*40];   // aeff^T [k][w][v], pads zero
    __shared__ unsigned short zsh[32*328];    // [w][j]
    __shared__ unsigned short gsh[25*68];     // g tile staging (padded rows)
    __shared__ float csum[160];
    __shared__ float sbc[320];

    const int tb = blockIdx.x, n = blockIdx.y;
    const int t0 = tb*10;
    const int tid = threadIdx.x;
    const int lane = tid & 63, wv = tid >> 6;
    const int lg = lane >> 4, lr = lane & 15;
    const int crow = lr + 16*wv;
    const int cbase = 16*wv + 4*lg;

    bf16x8 wfrag[10];
    #pragma unroll
    for (int ks = 0; ks < 10; ++ks)
        wfrag[ks] = *(const bf16x8*)&w2b[(ks*64 + crow)*32 + 8*lg];

    const float lam = lamda[0];
    for (int e = tid; e < 6400; e += 256) {
        int k = e / 1280, r = e % 1280, w = r / 40, v = r % 40;
        float val = 0.f;
        if (w < 25 && v < 25)
            val = (k < 3) ? A[k*625 + v*25 + w]
                          : lam * B[((n<<1) + (k-3))*625 + v*25 + w];
        ash[e] = f2bf(val);
    }
    for (int e = tid; e < 320; e += 256) sbc[e] = conv_b[e];
    __syncthreads();
    for (int e = tid; e < 160; e += 256) {
        int k = e / 32, w = e % 32;
        float s = 0.f;
        for (int v = 0; v < 25; ++v) s += bf2f(ash[k*1280 + w*40 + v]);
        csum[e] = s;
    }
    __syncthreads();

    float bs0[4], bs1[4];
    #pragma unroll
    for (int r = 0; r < 4; ++r) {
        float s0 = 0.f, s1 = 0.f;
        #pragma unroll
        for (int k = 0; k < 5; ++k) {
            float cb = sbc[k*64 + cbase + r];
            s0 += cb * csum[k*32 + lr];
            s1 += cb * csum[k*32 + lr + 16];
        }
        bs0[r] = s0; bs1[r] = s1;
    }

    float sacc[4] = {0,0,0,0}, qacc[4] = {0,0,0,0};

    const float* xrow = x + n*CTV + crow*TV + t0*V_;
    float xf[8];
    #pragma unroll
    for (int i = 0; i < 8; ++i) { int v = 8*lg + i; xf[i] = (v < 25) ? xrow[v] : 0.f; }

    for (int tl = 0; tl < 10; ++tl) {
        bf16x8 xfrag;
        #pragma unroll
        for (int i = 0; i < 8; ++i) xfrag[i] = (short)f2bf(xf[i]);
        if (tl < 9) {
            const float* xn = xrow + (tl+1)*V_;
            #pragma unroll
            for (int i = 0; i < 8; ++i) { int v = 8*lg + i; xf[i] = (v < 25) ? xn[v] : 0.f; }
        }
        // step 1: z tiles
        #pragma unroll
        for (int k = 0; k < 5; ++k)
        #pragma unroll
        for (int nt = 0; nt < 2; ++nt) {
            bf16x8 bfrag = *(const bf16x8*)&ash[k*1280 + (lr + 16*nt)*40 + 8*lg];
            f32x4 z = {0.f,0.f,0.f,0.f};
            z = __builtin_amdgcn_mfma_f32_16x16x32_bf16(xfrag, bfrag, z, 0, 0, 0);
            s4v z4;
            #pragma unroll
            for (int r = 0; r < 4; ++r) z4[r] = (short)f2bf(z[r]);
            *(s4v*)&zsh[(lr + 16*nt)*328 + k*64 + 16*wv + 4*lg] = z4;
        }
        __syncthreads();
        // step 2: g = W2 @ z
        f32x4 acc0 = {0.f,0.f,0.f,0.f}, acc1 = {0.f,0.f,0.f,0.f};
        #pragma unroll
        for (int ks = 0; ks < 10; ++ks) {
            bf16x8 b0 = *(const bf16x8*)&zsh[lr*328 + 32*ks + 8*lg];
            bf16x8 b1 = *(const bf16x8*)&zsh[(lr+16)*328 + 32*ks + 8*lg];
            acc0 = __builtin_amdgcn_mfma_f32_16x16x32_bf16(wfrag[ks], b0, acc0, 0, 0, 0);
            acc1 = __builtin_amdgcn_mfma_f32_16x16x32_bf16(wfrag[ks], b1, acc1, 0, 0, 0);
        }
        s4v g0, g1;
        #pragma unroll
        for (int r = 0; r < 4; ++r) {
            float v0 = acc0[r] + bs0[r];
            float v1 = acc1[r] + bs1[r];
            g0[r] = (short)f2bf(v0); g1[r] = (short)f2bf(v1);
            sacc[r] += v0 + (lr < 9 ? v1 : 0.f);
            qacc[r] += v0*v0 + (lr < 9 ? v1*v1 : 0.f);
        }
        *(s4v*)&gsh[lr*68 + cbase] = g0;
        if (lr < 9) *(s4v*)&gsh[(lr+16)*68 + cbase] = g1;
        __syncthreads();
        unsigned short* grow = gout + (size_t)(n*300 + t0 + tl)*1600;
        for (int e = tid; e < 1600; e += 256)
            grow[e] = gsh[(e >> 6)*68 + (e & 63)];
    }

    #pragma unroll
    for (int r = 0; r < 4; ++r) {
        float s = sacc[r], q = qacc[r];
        s += __shfl_xor(s, 1); s += __shfl_xor(s, 2);
        s += __shfl_xor(s, 4); s += __shfl_xor(s, 8);
        q += __shfl_xor(q, 1); q += __shfl_xor(q, 2);
        q += __shfl_xor(q, 4); q += __shfl_xor(q, 8);
        if (lr == 0) {
            stats3[(n*30 + tb)*128 + cbase + r] = s;
            stats3[(n*30 + tb)*128 + 64 + cbase + r] = q;
        }
    }
}

// ---------------------------------------------------------------------------
// k_fin: reduce per-block stats -> BN scale/shift. grid 64.
// ---------------------------------------------------------------------------
__global__ __launch_bounds__(256) void k_fin(
    const float* __restrict__ src, int count, float* __restrict__ sbo,
    const float* __restrict__ gma, const float* __restrict__ bta)
{
    const int c = blockIdx.x, tid = threadIdx.x;
    float s = 0.f, q = 0.f;
    for (int b = tid; b < count; b += 256) {
        s += src[b*128 + c];
        q += src[b*128 + 64 + c];
    }
    #pragma unroll
    for (int m = 1; m < 64; m <<= 1) { s += __shfl_xor(s, m); q += __shfl_xor(q, m); }
    __shared__ float rs[4], rq[4];
    if ((tid & 63) == 0) { rs[tid>>6] = s; rq[tid>>6] = q; }
    __syncthreads();
    if (tid == 0) {
        s = rs[0]+rs[1]+rs[2]+rs[3]; q = rq[0]+rq[1]+rq[2]+rq[3];
        float mean = s / CNTF, var = q / CNTF - mean*mean;
        float sc = gma[c] * rsqrtf(var + 1e-5f);
        sbo[c] = sc;
        sbo[64 + c] = bta[c] - mean*sc;
    }
}

// ---------------------------------------------------------------------------
// k_tcn: grid (38, 32). h = tconv(relu(bn1(g))) + tb, bf16 [n][c][t][w] + stats.
// ---------------------------------------------------------------------------
__global__ __launch_bounds__(256) void k_tcn(
    const unsigned short* __restrict__ gin, const float* __restrict__ sb,
    const unsigned short* __restrict__ twb, const float* __restrict__ tb,
    unsigned short* __restrict__ hout, float* __restrict__ stats4)
{
    __shared__ unsigned short pT[16*25*72];   // 57600 B, reused as hbuf f32
    __shared__ float sbs[128];

    const int n = blockIdx.y, tt = blockIdx.x, t0 = tt*8;
    const int tid = threadIdx.x;
    const int lane = tid & 63, wv = tid >> 6;
    const int lg = lane >> 4, lr = lane & 15;
    const int c = lr + 16*wv;
    const int cbase = 16*wv + 4*lg;

    bf16x8 af[18];
    #pragma unroll
    for (int gi = 0; gi < 18; ++gi)
        af[gi] = *(const bf16x8*)&twb[(gi*64 + c)*32 + 8*lg];

    for (int e = tid; e < 128; e += 256) sbs[e] = sb[e];
    __syncthreads();

    for (int e8 = tid; e8 < 3200; e8 += 256) {
        int tl = e8 / 200, r = e8 % 200, w = r >> 3, i8 = (r & 7) * 8;
        int tg = t0 - 4 + tl;
        s8v val8 = {0,0,0,0,0,0,0,0};
        if (tg >= 0 && tg < 300) {
            s8v raw = *(const s8v*)&gin[(size_t)((n*300 + tg)*25 + w)*64 + i8];
            #pragma unroll
            for (int j = 0; j < 8; ++j) {
                float f = fmaf(bf2f((unsigned short)raw[j]), sbs[i8+j], sbs[64+i8+j]);
                val8[j] = (short)f2bf(fmaxf(f, 0.f));
            }
        }
        *(s8v*)&pT[(tl*25 + w)*72 + i8] = val8;
    }
    __syncthreads();

    f32x4 acc[13];
    #pragma unroll
    for (int nt = 0; nt < 13; ++nt) {
        int col = lr + 16*nt; if (col > 199) col = 199;
        int tlo = (col*41) >> 10;
        int w = col - tlo*25;
        f32x4 a = {0.f,0.f,0.f,0.f};
        #pragma unroll
        for (int dt = 0; dt < 9; ++dt) {
            int rowbase = ((tlo + dt)*25 + w)*72 + 8*lg;
            bf16x8 b0 = *(const bf16x8*)&pT[rowbase];
            bf16x8 b1 = *(const bf16x8*)&pT[rowbase + 32];
            a = __builtin_amdgcn_mfma_f32_16x16x32_bf16(af[dt*2],     b0, a, 0, 0, 0);
            a = __builtin_amdgcn_mfma_f32_16x16x32_bf16(af[dt*2 + 1], b1, a, 0, 0, 0);
        }
        acc[nt] = a;
    }

    const int lim = min(200, (300 - t0)*25);
    float tbc[4];
    #pragma unroll
    for (int r = 0; r < 4; ++r) tbc[r] = tb[cbase + r];

    float sacc[4] = {0,0,0,0}, qacc[4] = {0,0,0,0};
    #pragma unroll
    for (int nt = 0; nt < 13; ++nt) {
        int col = lr + 16*nt;
        if (col < lim) {
            #pragma unroll
            for (int r = 0; r < 4; ++r) {
                float v = acc[nt][r] + tbc[r];
                sacc[r] += v; qacc[r] += v*v;
            }
        }
    }
    #pragma unroll
    for (int r = 0; r < 4; ++r) {
        float s = sacc[r], q = qacc[r];
        s += __shfl_xor(s, 1); s += __shfl_xor(s, 2);
        s += __shfl_xor(s, 4); s += __shfl_xor(s, 8);
        q += __shfl_xor(q, 1); q += __shfl_xor(q, 2);
        q += __shfl_xor(q, 4); q += __shfl_xor(q, 8);
        if (lr == 0) {
            stats4[(n*38 + tt)*128 + cbase + r] = s;
            stats4[(n*38 + tt)*128 + 64 + cbase + r] = q;
        }
    }

    __syncthreads();
    float* hbuf = (float*)pT;
    #pragma unroll
    for (int nt = 0; nt < 13; ++nt) {
        int col = lr + 16*nt;
        if (col < 200) {
            #pragma unroll
            for (int r = 0; r < 4; ++r)
                hbuf[(cbase + r)*200 + col] = acc[nt][r] + tbc[r];
        }
    }
    __syncthreads();
    for (int e2 = tid; e2 < 6400; e2 += 256) {
        int row = e2 / 100, c2 = (e2 - row*100)*2;
        if (c2 < lim) {
            float f0 = hbuf[row*200 + c2], f1 = hbuf[row*200 + c2 + 1];
            ushort2 o; o.x = f2bf(f0); o.y = f2bf(f1);
            *(ushort2*)&hout[((size_t)(n*64 + row)*300 + t0)*25 + c2] = o;
        }
    }
}

// ---------------------------------------------------------------------------
// k_out: out = relu(bn2(h) + x) f32
// ---------------------------------------------------------------------------
__global__ __launch_bounds__(256) void k_out(
    const unsigned short* __restrict__ h, const float* __restrict__ x,
    const float* __restrict__ sb, float* __restrict__ out)
{
    int i4 = blockIdx.x * 256 + threadIdx.x;
    if (i4 >= NELEM/4) return;
    int c = ((i4*4) / TV) & 63;
    float s2 = sb[128 + c], b2 = sb[192 + c];
    s4v hv = *(const s4v*)&h[i4*4];
    float4 xv = ((const float4*)x)[i4];
    float4 o;
    o.x = fmaxf(fmaf(bf2f((unsigned short)hv[0]), s2, b2) + xv.x, 0.f);
    o.y = fmaxf(fmaf(bf2f((unsigned short)hv[1]), s2, b2) + xv.y, 0.f);
    o.z = fmaxf(fmaf(bf2f((unsigned short)hv[2]), s2, b2) + xv.z, 0.f);
    o.w = fmaxf(fmaf(bf2f((unsigned short)hv[3]), s2, b2) + xv.w, 0.f);
    ((float4*)out)[i4] = o;
}

// ---------------------------------------------------------------------------
extern "C" void kernel_launch(void* const* d_in, const int* in_sizes, int n_in,
                              void* d_out, int out_size, void* d_ws, size_t ws_size,
                              hipStream_t stream)
{
    const float* x      = (const float*)d_in[0];
    const float* A      = (const float*)d_in[1];
    const float* B      = (const float*)d_in[2];
    const float* lamda  = (const float*)d_in[3];
    const float* conv_w = (const float*)d_in[4];
    const float* conv_b = (const float*)d_in[5];
    const float* bn1_g  = (const float*)d_in[6];
    const float* bn1_b  = (const float*)d_in[7];
    const float* tcn_w  = (const float*)d_in[8];
    const float* tcn_b  = (const float*)d_in[9];
    const float* bn2_g  = (const float*)d_in[10];
    const float* bn2_b  = (const float*)d_in[11];

    unsigned short* g = (unsigned short*)d_ws;          // NELEM bf16
    unsigned short* h = g + NELEM;                      // NELEM bf16
    float* stats3 = (float*)(h + NELEM);                // 960*128
    float* stats4 = stats3 + 960*128;                   // 1216*128
    float* sb     = stats4 + 1216*128;                  // 256
    unsigned short* w2b = (unsigned short*)(sb + 256);  // 20480
    unsigned short* twb = w2b + 20480;                  // 36864

    k_prep<<<32, 256, 0, stream>>>(conv_w, tcn_w, w2b, twb);
    k_gcn<<<dim3(30, N_), 256, 0, stream>>>(x, A, B, lamda, w2b, conv_b, g, stats3);
    k_fin<<<64, 256, 0, stream>>>(stats3, 960, sb, bn1_g, bn1_b);
    k_tcn<<<dim3(38, N_), 256, 0, stream>>>(g, sb, twb, tcn_b, h, stats4);
    k_fin<<<64, 256, 0, stream>>>(stats4, 1216, sb + 128, bn2_g, bn2_b);
    k_out<<<NELEM/4/256, 256, 0, stream>>>(h, x, sb, (float*)d_out);
}

// Round 5
// 144.425 us; speedup vs baseline: 6.3493x; 1.0026x over previous
//
#include <hip/hip_runtime.h>
#include <hip/hip_bf16.h>

#define N_  32
#define C_  64
#define T_  300
#define V_  25
#define TV  (T_*V_)        // 7500
#define CTV (C_*TV)        // 480000
#define NELEM (N_*CTV)     // 15360000
#define CNTF 240000.0f

typedef float f32x4 __attribute__((ext_vector_type(4)));
typedef short bf16x8 __attribute__((ext_vector_type(8)));
typedef short s4v __attribute__((ext_vector_type(4)));
typedef short s8v __attribute__((ext_vector_type(8)));

__device__ __forceinline__ unsigned short f2bf(float f) {
    unsigned u = __float_as_uint(f);
    unsigned r = u + 0x7fffu + ((u >> 16) & 1u);
    return (unsigned short)(r >> 16);
}
__device__ __forceinline__ float bf2f(unsigned short u) {
    return __uint_as_float(((unsigned)u) << 16);
}

// ---------------------------------------------------------------------------
// k_prep: one-time weight conversion to bf16 in MFMA A-frag friendly layouts.
// ---------------------------------------------------------------------------
__global__ __launch_bounds__(256) void k_prep(
    const float* __restrict__ conv_w, const float* __restrict__ tw,
    unsigned short* __restrict__ w2b, unsigned short* __restrict__ twb)
{
    int tid = blockIdx.x*256 + threadIdx.x;
    for (int e = tid; e < 20480; e += 8192) {
        int ks = e >> 11, c = (e >> 5) & 63, kk = e & 31;
        w2b[e] = f2bf(conv_w[(((ks>>1)*64 + c)*64) + (ks&1)*32 + kk]);
    }
    for (int e = tid; e < 36864; e += 8192) {
        int gi = e >> 11, c = (e >> 5) & 63, kk = e & 31;
        int dt = gi >> 1, ks = gi & 1;
        twb[e] = f2bf(tw[(c*64 + 32*ks + kk)*9 + dt]);
    }
}

// ---------------------------------------------------------------------------
// k_gcn: grid (30, 32), 10 t per block. (unchanged from round 4)
// ---------------------------------------------------------------------------
__global__ __launch_bounds__(256) void k_gcn(
    const float* __restrict__ x, const float* __restrict__ A,
    const float* __restrict__ B, const float* __restrict__ lamda,
    const unsigned short* __restrict__ w2b, const float* __restrict__ conv_b,
    unsigned short* __restrict__ gout, float* __restrict__ stats3)
{
    __shared__ unsigned short ash[5*32*40];
    __shared__ unsigned short zsh[32*328];
    __shared__ unsigned short gsh[25*68];
    __shared__ float csum[160];
    __shared__ float sbc[320];

    const int tb = blockIdx.x, n = blockIdx.y;
    const int t0 = tb*10;
    const int tid = threadIdx.x;
    const int lane = tid & 63, wv = tid >> 6;
    const int lg = lane >> 4, lr = lane & 15;
    const int crow = lr + 16*wv;
    const int cbase = 16*wv + 4*lg;

    bf16x8 wfrag[10];
    #pragma unroll
    for (int ks = 0; ks < 10; ++ks)
        wfrag[ks] = *(const bf16x8*)&w2b[(ks*64 + crow)*32 + 8*lg];

    const float lam = lamda[0];
    for (int e = tid; e < 6400; e += 256) {
        int k = e / 1280, r = e % 1280, w = r / 40, v = r % 40;
        float val = 0.f;
        if (w < 25 && v < 25)
            val = (k < 3) ? A[k*625 + v*25 + w]
                          : lam * B[((n<<1) + (k-3))*625 + v*25 + w];
        ash[e] = f2bf(val);
    }
    for (int e = tid; e < 320; e += 256) sbc[e] = conv_b[e];
    __syncthreads();
    for (int e = tid; e < 160; e += 256) {
        int k = e / 32, w = e % 32;
        float s = 0.f;
        for (int v = 0; v < 25; ++v) s += bf2f(ash[k*1280 + w*40 + v]);
        csum[e] = s;
    }
    __syncthreads();

    float bs0[4], bs1[4];
    #pragma unroll
    for (int r = 0; r < 4; ++r) {
        float s0 = 0.f, s1 = 0.f;
        #pragma unroll
        for (int k = 0; k < 5; ++k) {
            float cb = sbc[k*64 + cbase + r];
            s0 += cb * csum[k*32 + lr];
            s1 += cb * csum[k*32 + lr + 16];
        }
        bs0[r] = s0; bs1[r] = s1;
    }

    float sacc[4] = {0,0,0,0}, qacc[4] = {0,0,0,0};

    const float* xrow = x + n*CTV + crow*TV + t0*V_;
    float xf[8];
    #pragma unroll
    for (int i = 0; i < 8; ++i) { int v = 8*lg + i; xf[i] = (v < 25) ? xrow[v] : 0.f; }

    for (int tl = 0; tl < 10; ++tl) {
        bf16x8 xfrag;
        #pragma unroll
        for (int i = 0; i < 8; ++i) xfrag[i] = (short)f2bf(xf[i]);
        if (tl < 9) {
            const float* xn = xrow + (tl+1)*V_;
            #pragma unroll
            for (int i = 0; i < 8; ++i) { int v = 8*lg + i; xf[i] = (v < 25) ? xn[v] : 0.f; }
        }
        #pragma unroll
        for (int k = 0; k < 5; ++k)
        #pragma unroll
        for (int nt = 0; nt < 2; ++nt) {
            bf16x8 bfrag = *(const bf16x8*)&ash[k*1280 + (lr + 16*nt)*40 + 8*lg];
            f32x4 z = {0.f,0.f,0.f,0.f};
            z = __builtin_amdgcn_mfma_f32_16x16x32_bf16(xfrag, bfrag, z, 0, 0, 0);
            s4v z4;
            #pragma unroll
            for (int r = 0; r < 4; ++r) z4[r] = (short)f2bf(z[r]);
            *(s4v*)&zsh[(lr + 16*nt)*328 + k*64 + 16*wv + 4*lg] = z4;
        }
        __syncthreads();
        f32x4 acc0 = {0.f,0.f,0.f,0.f}, acc1 = {0.f,0.f,0.f,0.f};
        #pragma unroll
        for (int ks = 0; ks < 10; ++ks) {
            bf16x8 b0 = *(const bf16x8*)&zsh[lr*328 + 32*ks + 8*lg];
            bf16x8 b1 = *(const bf16x8*)&zsh[(lr+16)*328 + 32*ks + 8*lg];
            acc0 = __builtin_amdgcn_mfma_f32_16x16x32_bf16(wfrag[ks], b0, acc0, 0, 0, 0);
            acc1 = __builtin_amdgcn_mfma_f32_16x16x32_bf16(wfrag[ks], b1, acc1, 0, 0, 0);
        }
        s4v g0, g1;
        #pragma unroll
        for (int r = 0; r < 4; ++r) {
            float v0 = acc0[r] + bs0[r];
            float v1 = acc1[r] + bs1[r];
            g0[r] = (short)f2bf(v0); g1[r] = (short)f2bf(v1);
            sacc[r] += v0 + (lr < 9 ? v1 : 0.f);
            qacc[r] += v0*v0 + (lr < 9 ? v1*v1 : 0.f);
        }
        *(s4v*)&gsh[lr*68 + cbase] = g0;
        if (lr < 9) *(s4v*)&gsh[(lr+16)*68 + cbase] = g1;
        __syncthreads();
        unsigned short* grow = gout + (size_t)(n*300 + t0 + tl)*1600;
        for (int e = tid; e < 1600; e += 256)
            grow[e] = gsh[(e >> 6)*68 + (e & 63)];
    }

    #pragma unroll
    for (int r = 0; r < 4; ++r) {
        float s = sacc[r], q = qacc[r];
        s += __shfl_xor(s, 1); s += __shfl_xor(s, 2);
        s += __shfl_xor(s, 4); s += __shfl_xor(s, 8);
        q += __shfl_xor(q, 1); q += __shfl_xor(q, 2);
        q += __shfl_xor(q, 4); q += __shfl_xor(q, 8);
        if (lr == 0) {
            stats3[(n*30 + tb)*128 + cbase + r] = s;
            stats3[(n*30 + tb)*128 + 64 + cbase + r] = q;
        }
    }
}

// ---------------------------------------------------------------------------
// k_fin: reduce per-block stats -> BN scale/shift. grid 64.
// ---------------------------------------------------------------------------
__global__ __launch_bounds__(256) void k_fin(
    const float* __restrict__ src, int count, float* __restrict__ sbo,
    const float* __restrict__ gma, const float* __restrict__ bta)
{
    const int c = blockIdx.x, tid = threadIdx.x;
    float s = 0.f, q = 0.f;
    for (int b = tid; b < count; b += 256) {
        s += src[b*128 + c];
        q += src[b*128 + 64 + c];
    }
    #pragma unroll
    for (int m = 1; m < 64; m <<= 1) { s += __shfl_xor(s, m); q += __shfl_xor(q, m); }
    __shared__ float rs[4], rq[4];
    if ((tid & 63) == 0) { rs[tid>>6] = s; rq[tid>>6] = q; }
    __syncthreads();
    if (tid == 0) {
        s = rs[0]+rs[1]+rs[2]+rs[3]; q = rq[0]+rq[1]+rq[2]+rq[3];
        float mean = s / CNTF, var = q / CNTF - mean*mean;
        float sc = gma[c] * rsqrtf(var + 1e-5f);
        sbo[c] = sc;
        sbo[64 + c] = bta[c] - mean*sc;
    }
}

// ---------------------------------------------------------------------------
// k_tcn: grid (38, 32). i-dimension split into two K=32 rounds.
// pT[400 rows][40 shorts] (80B rows: 16B-aligned, bank-balanced), 32.0 KB.
// hbuf aliased into pT as bf16 [64][200]. 5 blocks/CU.
// ---------------------------------------------------------------------------
__global__ __launch_bounds__(256) void k_tcn(
    const unsigned short* __restrict__ gin, const float* __restrict__ sb,
    const unsigned short* __restrict__ twb, const float* __restrict__ tb,
    unsigned short* __restrict__ hout, float* __restrict__ stats4)
{
    __shared__ unsigned short pT[400*40];     // 32000 B; reused as bf16 hbuf[64][200]
    __shared__ float sbs[128];

    const int n = blockIdx.y, tt = blockIdx.x, t0 = tt*8;
    const int tid = threadIdx.x;
    const int lane = tid & 63, wv = tid >> 6;
    const int lg = lane >> 4, lr = lane & 15;
    const int c = lr + 16*wv;
    const int cbase = 16*wv + 4*lg;

    bf16x8 af[18];
    #pragma unroll
    for (int gi = 0; gi < 18; ++gi)
        af[gi] = *(const bf16x8*)&twb[(gi*64 + c)*32 + 8*lg];

    for (int e = tid; e < 128; e += 256) sbs[e] = sb[e];

    f32x4 acc[13];
    #pragma unroll
    for (int nt = 0; nt < 13; ++nt) acc[nt] = (f32x4){0.f,0.f,0.f,0.f};

    for (int ks = 0; ks < 2; ++ks) {
        __syncthreads();
        // stage half i-range: relu(bn1(g)) -> pT[(tl*25+w)*40 + ch*8]
        for (int e8 = tid; e8 < 1600; e8 += 256) {
            int tl = e8 / 100, r = e8 % 100, w = r >> 2, ch = r & 3;
            int tg = t0 - 4 + tl;
            int i8 = 32*ks + ch*8;
            s8v val8 = {0,0,0,0,0,0,0,0};
            if (tg >= 0 && tg < 300) {
                s8v raw = *(const s8v*)&gin[(size_t)((n*300 + tg)*25 + w)*64 + i8];
                #pragma unroll
                for (int j = 0; j < 8; ++j) {
                    float f = fmaf(bf2f((unsigned short)raw[j]), sbs[i8+j], sbs[64+i8+j]);
                    val8[j] = (short)f2bf(fmaxf(f, 0.f));
                }
            }
            *(s8v*)&pT[(tl*25 + w)*40 + ch*8] = val8;
        }
        __syncthreads();

        #pragma unroll
        for (int nt = 0; nt < 13; ++nt) {
            int col = lr + 16*nt; if (col > 199) col = 199;
            #pragma unroll
            for (int dt = 0; dt < 9; ++dt) {
                bf16x8 b = *(const bf16x8*)&pT[(col + 25*dt)*40 + 8*lg];
                acc[nt] = __builtin_amdgcn_mfma_f32_16x16x32_bf16(af[dt*2 + ks], b, acc[nt], 0, 0, 0);
            }
        }
    }

    const int lim = min(200, (300 - t0)*25);
    float tbc[4];
    #pragma unroll
    for (int r = 0; r < 4; ++r) tbc[r] = tb[cbase + r];

    // stats from accumulators (pre-quantization f32)
    float sacc[4] = {0,0,0,0}, qacc[4] = {0,0,0,0};
    #pragma unroll
    for (int nt = 0; nt < 13; ++nt) {
        int col = lr + 16*nt;
        if (col < lim) {
            #pragma unroll
            for (int r = 0; r < 4; ++r) {
                float v = acc[nt][r] + tbc[r];
                sacc[r] += v; qacc[r] += v*v;
            }
        }
    }
    #pragma unroll
    for (int r = 0; r < 4; ++r) {
        float s = sacc[r], q = qacc[r];
        s += __shfl_xor(s, 1); s += __shfl_xor(s, 2);
        s += __shfl_xor(s, 4); s += __shfl_xor(s, 8);
        q += __shfl_xor(q, 1); q += __shfl_xor(q, 2);
        q += __shfl_xor(q, 4); q += __shfl_xor(q, 8);
        if (lr == 0) {
            stats4[(n*38 + tt)*128 + cbase + r] = s;
            stats4[(n*38 + tt)*128 + 64 + cbase + r] = q;
        }
    }

    // transpose via bf16 hbuf (aliased onto pT), then coalesced s4v writes
    __syncthreads();
    unsigned short* hbuf = pT;   // [64][200] bf16 = 25600 B
    #pragma unroll
    for (int nt = 0; nt < 13; ++nt) {
        int col = lr + 16*nt;
        if (col < 200) {
            #pragma unroll
            for (int r = 0; r < 4; ++r)
                hbuf[(cbase + r)*200 + col] = f2bf(acc[nt][r] + tbc[r]);
        }
    }
    __syncthreads();
    for (int e = tid; e < 3200; e += 256) {
        int row = e / 50, c4 = (e % 50)*4;
        if (c4 < lim) {
            s4v o = *(const s4v*)&hbuf[row*200 + c4];
            *(s4v*)&hout[((size_t)(n*64 + row)*300 + t0)*25 + c4] = o;
        }
    }
}

// ---------------------------------------------------------------------------
// k_out: out = relu(bn2(h) + x) f32
// ---------------------------------------------------------------------------
__global__ __launch_bounds__(256) void k_out(
    const unsigned short* __restrict__ h, const float* __restrict__ x,
    const float* __restrict__ sb, float* __restrict__ out)
{
    int i4 = blockIdx.x * 256 + threadIdx.x;
    if (i4 >= NELEM/4) return;
    int c = ((i4*4) / TV) & 63;
    float s2 = sb[128 + c], b2 = sb[192 + c];
    s4v hv = *(const s4v*)&h[i4*4];
    float4 xv = ((const float4*)x)[i4];
    float4 o;
    o.x = fmaxf(fmaf(bf2f((unsigned short)hv[0]), s2, b2) + xv.x, 0.f);
    o.y = fmaxf(fmaf(bf2f((unsigned short)hv[1]), s2, b2) + xv.y, 0.f);
    o.z = fmaxf(fmaf(bf2f((unsigned short)hv[2]), s2, b2) + xv.z, 0.f);
    o.w = fmaxf(fmaf(bf2f((unsigned short)hv[3]), s2, b2) + xv.w, 0.f);
    ((float4*)out)[i4] = o;
}

// ---------------------------------------------------------------------------
extern "C" void kernel_launch(void* const* d_in, const int* in_sizes, int n_in,
                              void* d_out, int out_size, void* d_ws, size_t ws_size,
                              hipStream_t stream)
{
    const float* x      = (const float*)d_in[0];
    const float* A      = (const float*)d_in[1];
    const float* B      = (const float*)d_in[2];
    const float* lamda  = (const float*)d_in[3];
    const float* conv_w = (const float*)d_in[4];
    const float* conv_b = (const float*)d_in[5];
    const float* bn1_g  = (const float*)d_in[6];
    const float* bn1_b  = (const float*)d_in[7];
    const float* tcn_w  = (const float*)d_in[8];
    const float* tcn_b  = (const float*)d_in[9];
    const float* bn2_g  = (const float*)d_in[10];
    const float* bn2_b  = (const float*)d_in[11];

    unsigned short* g = (unsigned short*)d_ws;          // NELEM bf16
    unsigned short* h = g + NELEM;                      // NELEM bf16
    float* stats3 = (float*)(h + NELEM);                // 960*128
    float* stats4 = stats3 + 960*128;                   // 1216*128
    float* sb     = stats4 + 1216*128;                  // 256
    unsigned short* w2b = (unsigned short*)(sb + 256);  // 20480
    unsigned short* twb = w2b + 20480;                  // 36864

    k_prep<<<32, 256, 0, stream>>>(conv_w, tcn_w, w2b, twb);
    k_gcn<<<dim3(30, N_), 256, 0, stream>>>(x, A, B, lamda, w2b, conv_b, g, stats3);
    k_fin<<<64, 256, 0, stream>>>(stats3, 960, sb, bn1_g, bn1_b);
    k_tcn<<<dim3(38, N_), 256, 0, stream>>>(g, sb, twb, tcn_b, h, stats4);
    k_fin<<<64, 256, 0, stream>>>(stats4, 1216, sb + 128, bn2_g, bn2_b);
    k_out<<<NELEM/4/256, 256, 0, stream>>>(h, x, sb, (float*)d_out);
}

// Round 6
// 138.188 us; speedup vs baseline: 6.6359x; 1.0451x over previous
//
#include <hip/hip_runtime.h>
#include <hip/hip_bf16.h>

#define N_  32
#define C_  64
#define T_  300
#define V_  25
#define TV  (T_*V_)        // 7500
#define CTV (C_*TV)        // 480000
#define NELEM (N_*CTV)     // 15360000
#define CNTF 240000.0f

typedef float f32x4 __attribute__((ext_vector_type(4)));
typedef short bf16x8 __attribute__((ext_vector_type(8)));
typedef short s4v __attribute__((ext_vector_type(4)));
typedef short s8v __attribute__((ext_vector_type(8)));

__device__ __forceinline__ unsigned short f2bf(float f) {
    unsigned u = __float_as_uint(f);
    unsigned r = u + 0x7fffu + ((u >> 16) & 1u);
    return (unsigned short)(r >> 16);
}
__device__ __forceinline__ float bf2f(unsigned short u) {
    return __uint_as_float(((unsigned)u) << 16);
}

// ---------------------------------------------------------------------------
// k_prep: one-time weight conversion to bf16 in MFMA A-frag friendly layouts.
// ---------------------------------------------------------------------------
__global__ __launch_bounds__(256) void k_prep(
    const float* __restrict__ conv_w, const float* __restrict__ tw,
    unsigned short* __restrict__ w2b, unsigned short* __restrict__ twb)
{
    int tid = blockIdx.x*256 + threadIdx.x;
    for (int e = tid; e < 20480; e += 8192) {
        int ks = e >> 11, c = (e >> 5) & 63, kk = e & 31;
        w2b[e] = f2bf(conv_w[(((ks>>1)*64 + c)*64) + (ks&1)*32 + kk]);
    }
    for (int e = tid; e < 36864; e += 8192) {
        int gi = e >> 11, c = (e >> 5) & 63, kk = e & 31;
        int dt = gi >> 1, ks = gi & 1;
        twb[e] = f2bf(tw[(c*64 + 32*ks + kk)*9 + dt]);
    }
}

// ---------------------------------------------------------------------------
// k_gcn: grid (30, 32), 10 t per block. (unchanged)
// ---------------------------------------------------------------------------
__global__ __launch_bounds__(256) void k_gcn(
    const float* __restrict__ x, const float* __restrict__ A,
    const float* __restrict__ B, const float* __restrict__ lamda,
    const unsigned short* __restrict__ w2b, const float* __restrict__ conv_b,
    unsigned short* __restrict__ gout, float* __restrict__ stats3)
{
    __shared__ unsigned short ash[5*32*40];
    __shared__ unsigned short zsh[32*328];
    __shared__ unsigned short gsh[25*68];
    __shared__ float csum[160];
    __shared__ float sbc[320];

    const int tb = blockIdx.x, n = blockIdx.y;
    const int t0 = tb*10;
    const int tid = threadIdx.x;
    const int lane = tid & 63, wv = tid >> 6;
    const int lg = lane >> 4, lr = lane & 15;
    const int crow = lr + 16*wv;
    const int cbase = 16*wv + 4*lg;

    bf16x8 wfrag[10];
    #pragma unroll
    for (int ks = 0; ks < 10; ++ks)
        wfrag[ks] = *(const bf16x8*)&w2b[(ks*64 + crow)*32 + 8*lg];

    const float lam = lamda[0];
    for (int e = tid; e < 6400; e += 256) {
        int k = e / 1280, r = e % 1280, w = r / 40, v = r % 40;
        float val = 0.f;
        if (w < 25 && v < 25)
            val = (k < 3) ? A[k*625 + v*25 + w]
                          : lam * B[((n<<1) + (k-3))*625 + v*25 + w];
        ash[e] = f2bf(val);
    }
    for (int e = tid; e < 320; e += 256) sbc[e] = conv_b[e];
    __syncthreads();
    for (int e = tid; e < 160; e += 256) {
        int k = e / 32, w = e % 32;
        float s = 0.f;
        for (int v = 0; v < 25; ++v) s += bf2f(ash[k*1280 + w*40 + v]);
        csum[e] = s;
    }
    __syncthreads();

    float bs0[4], bs1[4];
    #pragma unroll
    for (int r = 0; r < 4; ++r) {
        float s0 = 0.f, s1 = 0.f;
        #pragma unroll
        for (int k = 0; k < 5; ++k) {
            float cb = sbc[k*64 + cbase + r];
            s0 += cb * csum[k*32 + lr];
            s1 += cb * csum[k*32 + lr + 16];
        }
        bs0[r] = s0; bs1[r] = s1;
    }

    float sacc[4] = {0,0,0,0}, qacc[4] = {0,0,0,0};

    const float* xrow = x + n*CTV + crow*TV + t0*V_;
    float xf[8];
    #pragma unroll
    for (int i = 0; i < 8; ++i) { int v = 8*lg + i; xf[i] = (v < 25) ? xrow[v] : 0.f; }

    for (int tl = 0; tl < 10; ++tl) {
        bf16x8 xfrag;
        #pragma unroll
        for (int i = 0; i < 8; ++i) xfrag[i] = (short)f2bf(xf[i]);
        if (tl < 9) {
            const float* xn = xrow + (tl+1)*V_;
            #pragma unroll
            for (int i = 0; i < 8; ++i) { int v = 8*lg + i; xf[i] = (v < 25) ? xn[v] : 0.f; }
        }
        #pragma unroll
        for (int k = 0; k < 5; ++k)
        #pragma unroll
        for (int nt = 0; nt < 2; ++nt) {
            bf16x8 bfrag = *(const bf16x8*)&ash[k*1280 + (lr + 16*nt)*40 + 8*lg];
            f32x4 z = {0.f,0.f,0.f,0.f};
            z = __builtin_amdgcn_mfma_f32_16x16x32_bf16(xfrag, bfrag, z, 0, 0, 0);
            s4v z4;
            #pragma unroll
            for (int r = 0; r < 4; ++r) z4[r] = (short)f2bf(z[r]);
            *(s4v*)&zsh[(lr + 16*nt)*328 + k*64 + 16*wv + 4*lg] = z4;
        }
        __syncthreads();
        f32x4 acc0 = {0.f,0.f,0.f,0.f}, acc1 = {0.f,0.f,0.f,0.f};
        #pragma unroll
        for (int ks = 0; ks < 10; ++ks) {
            bf16x8 b0 = *(const bf16x8*)&zsh[lr*328 + 32*ks + 8*lg];
            bf16x8 b1 = *(const bf16x8*)&zsh[(lr+16)*328 + 32*ks + 8*lg];
            acc0 = __builtin_amdgcn_mfma_f32_16x16x32_bf16(wfrag[ks], b0, acc0, 0, 0, 0);
            acc1 = __builtin_amdgcn_mfma_f32_16x16x32_bf16(wfrag[ks], b1, acc1, 0, 0, 0);
        }
        s4v g0, g1;
        #pragma unroll
        for (int r = 0; r < 4; ++r) {
            float v0 = acc0[r] + bs0[r];
            float v1 = acc1[r] + bs1[r];
            g0[r] = (short)f2bf(v0); g1[r] = (short)f2bf(v1);
            sacc[r] += v0 + (lr < 9 ? v1 : 0.f);
            qacc[r] += v0*v0 + (lr < 9 ? v1*v1 : 0.f);
        }
        *(s4v*)&gsh[lr*68 + cbase] = g0;
        if (lr < 9) *(s4v*)&gsh[(lr+16)*68 + cbase] = g1;
        __syncthreads();
        unsigned short* grow = gout + (size_t)(n*300 + t0 + tl)*1600;
        for (int e = tid; e < 1600; e += 256)
            grow[e] = gsh[(e >> 6)*68 + (e & 63)];
    }

    #pragma unroll
    for (int r = 0; r < 4; ++r) {
        float s = sacc[r], q = qacc[r];
        s += __shfl_xor(s, 1); s += __shfl_xor(s, 2);
        s += __shfl_xor(s, 4); s += __shfl_xor(s, 8);
        q += __shfl_xor(q, 1); q += __shfl_xor(q, 2);
        q += __shfl_xor(q, 4); q += __shfl_xor(q, 8);
        if (lr == 0) {
            stats3[(n*30 + tb)*128 + cbase + r] = s;
            stats3[(n*30 + tb)*128 + 64 + cbase + r] = q;
        }
    }
}

// ---------------------------------------------------------------------------
// k_fin: reduce per-block stats -> BN scale/shift. grid 64.
// ---------------------------------------------------------------------------
__global__ __launch_bounds__(256) void k_fin(
    const float* __restrict__ src, int count, float* __restrict__ sbo,
    const float* __restrict__ gma, const float* __restrict__ bta)
{
    const int c = blockIdx.x, tid = threadIdx.x;
    float s = 0.f, q = 0.f;
    for (int b = tid; b < count; b += 256) {
        s += src[b*128 + c];
        q += src[b*128 + 64 + c];
    }
    #pragma unroll
    for (int m = 1; m < 64; m <<= 1) { s += __shfl_xor(s, m); q += __shfl_xor(q, m); }
    __shared__ float rs[4], rq[4];
    if ((tid & 63) == 0) { rs[tid>>6] = s; rq[tid>>6] = q; }
    __syncthreads();
    if (tid == 0) {
        s = rs[0]+rs[1]+rs[2]+rs[3]; q = rq[0]+rq[1]+rq[2]+rq[3];
        float mean = s / CNTF, var = q / CNTF - mean*mean;
        float sc = gma[c] * rsqrtf(var + 1e-5f);
        sbo[c] = sc;
        sbo[64 + c] = bta[c] - mean*sc;
    }
}

// ---------------------------------------------------------------------------
// k_tcn v3: grid (38, 32), 512 threads = 8 waves.
// Wave w: c-tile ct = w&3 (A-frags for current ks only: 9 regs-of-4),
//         col-half ch = w>>2: 7 col-tiles each (acc 7 x f32x4 = 28 regs).
// pT[400][40] shorts (32 KB) double-pass over i (ks=0,1).
// Per-(block,ch) stats partials; bf16 hbuf transpose epilogue.
// ---------------------------------------------------------------------------
__global__ __launch_bounds__(512, 4) void k_tcn(
    const unsigned short* __restrict__ gin, const float* __restrict__ sb,
    const unsigned short* __restrict__ twb, const float* __restrict__ tb,
    unsigned short* __restrict__ hout, float* __restrict__ stats4)
{
    __shared__ unsigned short pT[400*40];     // 32000 B; reused as bf16 hbuf[64][200]
    __shared__ float sbs[128];

    const int n = blockIdx.y, tt = blockIdx.x, t0 = tt*8;
    const int tid = threadIdx.x;
    const int lane = tid & 63, wv = tid >> 6;   // 8 waves
    const int lg = lane >> 4, lr = lane & 15;
    const int ct = wv & 3, ch = wv >> 2;
    const int cfrag = ct*16 + lr;               // A-frag row (c)
    const int cbase = ct*16 + 4*lg;             // D row base (c)

    for (int e = tid; e < 128; e += 512) sbs[e] = sb[e];

    f32x4 acc[7];
    #pragma unroll
    for (int i = 0; i < 7; ++i) acc[i] = (f32x4){0.f,0.f,0.f,0.f};

    for (int ks = 0; ks < 2; ++ks) {
        // A-frags for this ks (from L2-hot twb): 9 x 4 VGPR
        bf16x8 af[9];
        #pragma unroll
        for (int dt = 0; dt < 9; ++dt)
            af[dt] = *(const bf16x8*)&twb[((dt*2 + ks)*64 + cfrag)*32 + 8*lg];

        __syncthreads();
        // stage half i-range: relu(bn1(g)) -> pT[(tl*25+w)*40 + c8*8]
        for (int e8 = tid; e8 < 1600; e8 += 512) {
            int tl = e8 / 100, r = e8 % 100, w = r >> 2, c8 = r & 3;
            int tg = t0 - 4 + tl;
            int i8 = 32*ks + c8*8;
            s8v val8 = {0,0,0,0,0,0,0,0};
            if (tg >= 0 && tg < 300) {
                s8v raw = *(const s8v*)&gin[(size_t)((n*300 + tg)*25 + w)*64 + i8];
                #pragma unroll
                for (int j = 0; j < 8; ++j) {
                    float f = fmaf(bf2f((unsigned short)raw[j]), sbs[i8+j], sbs[64+i8+j]);
                    val8[j] = (short)f2bf(fmaxf(f, 0.f));
                }
            }
            *(s8v*)&pT[(tl*25 + w)*40 + c8*8] = val8;
        }
        __syncthreads();

        #pragma unroll
        for (int i = 0; i < 7; ++i) {
            int col = lr + 16*(ch*7 + i); if (col > 199) col = 199;
            #pragma unroll
            for (int dt = 0; dt < 9; ++dt) {
                bf16x8 b = *(const bf16x8*)&pT[(col + 25*dt)*40 + 8*lg];
                acc[i] = __builtin_amdgcn_mfma_f32_16x16x32_bf16(af[dt], b, acc[i], 0, 0, 0);
            }
        }
    }

    const int lim = min(200, (300 - t0)*25);
    float tbc[4];
    #pragma unroll
    for (int r = 0; r < 4; ++r) tbc[r] = tb[cbase + r];

    // stats partials (per block, per col-half)
    float sacc[4] = {0,0,0,0}, qacc[4] = {0,0,0,0};
    #pragma unroll
    for (int i = 0; i < 7; ++i) {
        int col = lr + 16*(ch*7 + i);
        if (col < lim) {
            #pragma unroll
            for (int r = 0; r < 4; ++r) {
                float v = acc[i][r] + tbc[r];
                sacc[r] += v; qacc[r] += v*v;
            }
        }
    }
    #pragma unroll
    for (int r = 0; r < 4; ++r) {
        float s = sacc[r], q = qacc[r];
        s += __shfl_xor(s, 1); s += __shfl_xor(s, 2);
        s += __shfl_xor(s, 4); s += __shfl_xor(s, 8);
        q += __shfl_xor(q, 1); q += __shfl_xor(q, 2);
        q += __shfl_xor(q, 4); q += __shfl_xor(q, 8);
        if (lr == 0) {
            float* dst = stats4 + (size_t)((n*38 + tt)*2 + ch)*128;
            dst[cbase + r] = s;
            dst[64 + cbase + r] = q;
        }
    }

    // transpose via bf16 hbuf (aliased onto pT), then coalesced s4v writes
    __syncthreads();
    unsigned short* hbuf = pT;   // [64][200] bf16 = 25600 B
    #pragma unroll
    for (int i = 0; i < 7; ++i) {
        int col = lr + 16*(ch*7 + i);
        if (col < 200) {
            #pragma unroll
            for (int r = 0; r < 4; ++r)
                hbuf[(cbase + r)*200 + col] = f2bf(acc[i][r] + tbc[r]);
        }
    }
    __syncthreads();
    for (int e = tid; e < 3200; e += 512) {
        int row = e / 50, c4 = (e % 50)*4;
        if (c4 < lim) {
            s4v o = *(const s4v*)&hbuf[row*200 + c4];
            *(s4v*)&hout[((size_t)(n*64 + row)*300 + t0)*25 + c4] = o;
        }
    }
}

// ---------------------------------------------------------------------------
// k_out: out = relu(bn2(h) + x) f32
// ---------------------------------------------------------------------------
__global__ __launch_bounds__(256) void k_out(
    const unsigned short* __restrict__ h, const float* __restrict__ x,
    const float* __restrict__ sb, float* __restrict__ out)
{
    int i4 = blockIdx.x * 256 + threadIdx.x;
    if (i4 >= NELEM/4) return;
    int c = ((i4*4) / TV) & 63;
    float s2 = sb[128 + c], b2 = sb[192 + c];
    s4v hv = *(const s4v*)&h[i4*4];
    float4 xv = ((const float4*)x)[i4];
    float4 o;
    o.x = fmaxf(fmaf(bf2f((unsigned short)hv[0]), s2, b2) + xv.x, 0.f);
    o.y = fmaxf(fmaf(bf2f((unsigned short)hv[1]), s2, b2) + xv.y, 0.f);
    o.z = fmaxf(fmaf(bf2f((unsigned short)hv[2]), s2, b2) + xv.z, 0.f);
    o.w = fmaxf(fmaf(bf2f((unsigned short)hv[3]), s2, b2) + xv.w, 0.f);
    ((float4*)out)[i4] = o;
}

// ---------------------------------------------------------------------------
extern "C" void kernel_launch(void* const* d_in, const int* in_sizes, int n_in,
                              void* d_out, int out_size, void* d_ws, size_t ws_size,
                              hipStream_t stream)
{
    const float* x      = (const float*)d_in[0];
    const float* A      = (const float*)d_in[1];
    const float* B      = (const float*)d_in[2];
    const float* lamda  = (const float*)d_in[3];
    const float* conv_w = (const float*)d_in[4];
    const float* conv_b = (const float*)d_in[5];
    const float* bn1_g  = (const float*)d_in[6];
    const float* bn1_b  = (const float*)d_in[7];
    const float* tcn_w  = (const float*)d_in[8];
    const float* tcn_b  = (const float*)d_in[9];
    const float* bn2_g  = (const float*)d_in[10];
    const float* bn2_b  = (const float*)d_in[11];

    unsigned short* g = (unsigned short*)d_ws;          // NELEM bf16
    unsigned short* h = g + NELEM;                      // NELEM bf16
    float* stats3 = (float*)(h + NELEM);                // 960*128
    float* stats4 = stats3 + 960*128;                   // 2432*128
    float* sb     = stats4 + 2432*128;                  // 256
    unsigned short* w2b = (unsigned short*)(sb + 256);  // 20480
    unsigned short* twb = w2b + 20480;                  // 36864

    k_prep<<<32, 256, 0, stream>>>(conv_w, tcn_w, w2b, twb);
    k_gcn<<<dim3(30, N_), 256, 0, stream>>>(x, A, B, lamda, w2b, conv_b, g, stats3);
    k_fin<<<64, 256, 0, stream>>>(stats3, 960, sb, bn1_g, bn1_b);
    k_tcn<<<dim3(38, N_), 512, 0, stream>>>(g, sb, twb, tcn_b, h, stats4);
    k_fin<<<64, 256, 0, stream>>>(stats4, 2432, sb + 128, bn2_g, bn2_b);
    k_out<<<NELEM/4/256, 256, 0, stream>>>(h, x, sb, (float*)d_out);
}

// Round 7
// 134.737 us; speedup vs baseline: 6.8059x; 1.0256x over previous
//
#include <hip/hip_runtime.h>
#include <hip/hip_bf16.h>

#define N_  32
#define C_  64
#define T_  300
#define V_  25
#define TV  (T_*V_)        // 7500
#define CTV (C_*TV)        // 480000
#define NELEM (N_*CTV)     // 15360000
#define CNTF 240000.0f

typedef float f32x4 __attribute__((ext_vector_type(4)));
typedef short bf16x8 __attribute__((ext_vector_type(8)));
typedef short s4v __attribute__((ext_vector_type(4)));
typedef short s8v __attribute__((ext_vector_type(8)));

__device__ __forceinline__ unsigned short f2bf(float f) {
    unsigned u = __float_as_uint(f);
    unsigned r = u + 0x7fffu + ((u >> 16) & 1u);
    return (unsigned short)(r >> 16);
}
__device__ __forceinline__ float bf2f(unsigned short u) {
    return __uint_as_float(((unsigned)u) << 16);
}
// HW packed f32->bf16 (RNE), lo in [15:0], hi in [31:16]
__device__ __forceinline__ unsigned cvt_pk(float lo, float hi) {
    unsigned r;
    asm("v_cvt_pk_bf16_f32 %0, %1, %2" : "=v"(r) : "v"(lo), "v"(hi));
    return r;
}

// ---------------------------------------------------------------------------
// k_prep: one-time weight conversion to bf16 in MFMA A-frag friendly layouts.
// ---------------------------------------------------------------------------
__global__ __launch_bounds__(256) void k_prep(
    const float* __restrict__ conv_w, const float* __restrict__ tw,
    unsigned short* __restrict__ w2b, unsigned short* __restrict__ twb)
{
    int tid = blockIdx.x*256 + threadIdx.x;
    for (int e = tid; e < 20480; e += 8192) {
        int ks = e >> 11, c = (e >> 5) & 63, kk = e & 31;
        w2b[e] = f2bf(conv_w[(((ks>>1)*64 + c)*64) + (ks&1)*32 + kk]);
    }
    for (int e = tid; e < 36864; e += 8192) {
        int gi = e >> 11, c = (e >> 5) & 63, kk = e & 31;
        int dt = gi >> 1, ks = gi & 1;
        twb[e] = f2bf(tw[(c*64 + 32*ks + kk)*9 + dt]);
    }
}

// ---------------------------------------------------------------------------
// k_gcn: grid (30, 32), 10 t per block. cvt_pk hot paths, direct g stores.
// ---------------------------------------------------------------------------
__global__ __launch_bounds__(256) void k_gcn(
    const float* __restrict__ x, const float* __restrict__ A,
    const float* __restrict__ B, const float* __restrict__ lamda,
    const unsigned short* __restrict__ w2b, const float* __restrict__ conv_b,
    unsigned short* __restrict__ gout, float* __restrict__ stats3)
{
    __shared__ unsigned short ash[5*32*40];   // aeff^T [k][w][v], pads zero
    __shared__ unsigned short zsh[32*328];    // [w][j]
    __shared__ float csum[160];
    __shared__ float sbc[320];

    const int tb = blockIdx.x, n = blockIdx.y;
    const int t0 = tb*10;
    const int tid = threadIdx.x;
    const int lane = tid & 63, wv = tid >> 6;
    const int lg = lane >> 4, lr = lane & 15;
    const int crow = lr + 16*wv;
    const int cbase = 16*wv + 4*lg;

    bf16x8 wfrag[10];
    #pragma unroll
    for (int ks = 0; ks < 10; ++ks)
        wfrag[ks] = *(const bf16x8*)&w2b[(ks*64 + crow)*32 + 8*lg];

    const float lam = lamda[0];
    // zero-prefill ash (covers pads), then fill from contiguous A/B reads
    {
        s8v z8 = {0,0,0,0,0,0,0,0};
        for (int e = tid; e < 800; e += 256) *(s8v*)&ash[e*8] = z8;
    }
    for (int e = tid; e < 320; e += 256) sbc[e] = conv_b[e];
    __syncthreads();
    for (int e = tid; e < 3125; e += 256) {
        int k = e / 625, r = e - k*625;
        int v = r / 25, w = r - v*25;
        float val = (k < 3) ? A[e] : lam * B[((n<<1) + (k-3))*625 + r];
        ash[k*1280 + w*40 + v] = f2bf(val);
    }
    __syncthreads();
    for (int e = tid; e < 160; e += 256) {
        int k = e / 32, w = e % 32;
        float s = 0.f;
        for (int v = 0; v < 25; ++v) s += bf2f(ash[k*1280 + w*40 + v]);
        csum[e] = s;
    }
    __syncthreads();

    float bs0[4], bs1[4];
    #pragma unroll
    for (int r = 0; r < 4; ++r) {
        float s0 = 0.f, s1 = 0.f;
        #pragma unroll
        for (int k = 0; k < 5; ++k) {
            float cb = sbc[k*64 + cbase + r];
            s0 += cb * csum[k*32 + lr];
            s1 += cb * csum[k*32 + lr + 16];
        }
        bs0[r] = s0; bs1[r] = s1;
    }

    float sacc[4] = {0,0,0,0}, qacc[4] = {0,0,0,0};

    const float* xrow = x + n*CTV + crow*TV + t0*V_;
    float xf[8];
    #pragma unroll
    for (int i = 0; i < 8; ++i) { int v = 8*lg + i; xf[i] = (v < 25) ? xrow[v] : 0.f; }

    for (int tl = 0; tl < 10; ++tl) {
        union { bf16x8 v; unsigned u[4]; } xu;
        #pragma unroll
        for (int p = 0; p < 4; ++p) xu.u[p] = cvt_pk(xf[2*p], xf[2*p+1]);
        bf16x8 xfrag = xu.v;
        if (tl < 9) {
            const float* xn = xrow + (tl+1)*V_;
            #pragma unroll
            for (int i = 0; i < 8; ++i) { int v = 8*lg + i; xf[i] = (v < 25) ? xn[v] : 0.f; }
        }
        // step 1: z tiles -> zsh (packed via cvt_pk)
        #pragma unroll
        for (int k = 0; k < 5; ++k)
        #pragma unroll
        for (int nt = 0; nt < 2; ++nt) {
            bf16x8 bfrag = *(const bf16x8*)&ash[k*1280 + (lr + 16*nt)*40 + 8*lg];
            f32x4 z = {0.f,0.f,0.f,0.f};
            z = __builtin_amdgcn_mfma_f32_16x16x32_bf16(xfrag, bfrag, z, 0, 0, 0);
            uint2 zz;
            zz.x = cvt_pk(z[0], z[1]);
            zz.y = cvt_pk(z[2], z[3]);
            *(uint2*)&zsh[(lr + 16*nt)*328 + k*64 + 16*wv + 4*lg] = zz;
        }
        __syncthreads();
        // step 2: g = W2 @ z
        f32x4 acc0 = {0.f,0.f,0.f,0.f}, acc1 = {0.f,0.f,0.f,0.f};
        #pragma unroll
        for (int ks = 0; ks < 10; ++ks) {
            bf16x8 b0 = *(const bf16x8*)&zsh[lr*328 + 32*ks + 8*lg];
            bf16x8 b1 = *(const bf16x8*)&zsh[(lr+16)*328 + 32*ks + 8*lg];
            acc0 = __builtin_amdgcn_mfma_f32_16x16x32_bf16(wfrag[ks], b0, acc0, 0, 0, 0);
            acc1 = __builtin_amdgcn_mfma_f32_16x16x32_bf16(wfrag[ks], b1, acc1, 0, 0, 0);
        }
        // epilogue: bias, stats, direct global stores
        float v0a[4], v1a[4];
        #pragma unroll
        for (int r = 0; r < 4; ++r) {
            v0a[r] = acc0[r] + bs0[r];
            v1a[r] = acc1[r] + bs1[r];
            sacc[r] += v0a[r] + (lr < 9 ? v1a[r] : 0.f);
            qacc[r] += v0a[r]*v0a[r] + (lr < 9 ? v1a[r]*v1a[r] : 0.f);
        }
        unsigned short* grow = gout + (size_t)(n*300 + t0 + tl)*1600;
        uint2 g0, g1;
        g0.x = cvt_pk(v0a[0], v0a[1]); g0.y = cvt_pk(v0a[2], v0a[3]);
        g1.x = cvt_pk(v1a[0], v1a[1]); g1.y = cvt_pk(v1a[2], v1a[3]);
        *(uint2*)&grow[lr*64 + cbase] = g0;
        if (lr < 9) *(uint2*)&grow[(lr+16)*64 + cbase] = g1;
        __syncthreads();
    }

    #pragma unroll
    for (int r = 0; r < 4; ++r) {
        float s = sacc[r], q = qacc[r];
        s += __shfl_xor(s, 1); s += __shfl_xor(s, 2);
        s += __shfl_xor(s, 4); s += __shfl_xor(s, 8);
        q += __shfl_xor(q, 1); q += __shfl_xor(q, 2);
        q += __shfl_xor(q, 4); q += __shfl_xor(q, 8);
        if (lr == 0) {
            stats3[(n*30 + tb)*128 + cbase + r] = s;
            stats3[(n*30 + tb)*128 + 64 + cbase + r] = q;
        }
    }
}

// ---------------------------------------------------------------------------
// k_fin: reduce per-block stats -> BN scale/shift. grid 64.
// ---------------------------------------------------------------------------
__global__ __launch_bounds__(256) void k_fin(
    const float* __restrict__ src, int count, float* __restrict__ sbo,
    const float* __restrict__ gma, const float* __restrict__ bta)
{
    const int c = blockIdx.x, tid = threadIdx.x;
    float s = 0.f, q = 0.f;
    for (int b = tid; b < count; b += 256) {
        s += src[b*128 + c];
        q += src[b*128 + 64 + c];
    }
    #pragma unroll
    for (int m = 1; m < 64; m <<= 1) { s += __shfl_xor(s, m); q += __shfl_xor(q, m); }
    __shared__ float rs[4], rq[4];
    if ((tid & 63) == 0) { rs[tid>>6] = s; rq[tid>>6] = q; }
    __syncthreads();
    if (tid == 0) {
        s = rs[0]+rs[1]+rs[2]+rs[3]; q = rq[0]+rq[1]+rq[2]+rq[3];
        float mean = s / CNTF, var = q / CNTF - mean*mean;
        float sc = gma[c] * rsqrtf(var + 1e-5f);
        sbo[c] = sc;
        sbo[64 + c] = bta[c] - mean*sc;
    }
}

// ---------------------------------------------------------------------------
// k_tcn: grid (38, 32), 512 threads = 8 waves. (round-6 structure + cvt_pk)
// ---------------------------------------------------------------------------
__global__ __launch_bounds__(512, 4) void k_tcn(
    const unsigned short* __restrict__ gin, const float* __restrict__ sb,
    const unsigned short* __restrict__ twb, const float* __restrict__ tb,
    unsigned short* __restrict__ hout, float* __restrict__ stats4)
{
    __shared__ unsigned short pT[400*40];     // 32000 B; reused as bf16 hbuf[64][200]
    __shared__ float sbs[128];

    const int n = blockIdx.y, tt = blockIdx.x, t0 = tt*8;
    const int tid = threadIdx.x;
    const int lane = tid & 63, wv = tid >> 6;   // 8 waves
    const int lg = lane >> 4, lr = lane & 15;
    const int ct = wv & 3, ch = wv >> 2;
    const int cfrag = ct*16 + lr;               // A-frag row (c)
    const int cbase = ct*16 + 4*lg;             // D row base (c)

    for (int e = tid; e < 128; e += 512) sbs[e] = sb[e];

    f32x4 acc[7];
    #pragma unroll
    for (int i = 0; i < 7; ++i) acc[i] = (f32x4){0.f,0.f,0.f,0.f};

    for (int ks = 0; ks < 2; ++ks) {
        bf16x8 af[9];
        #pragma unroll
        for (int dt = 0; dt < 9; ++dt)
            af[dt] = *(const bf16x8*)&twb[((dt*2 + ks)*64 + cfrag)*32 + 8*lg];

        __syncthreads();
        for (int e8 = tid; e8 < 1600; e8 += 512) {
            int tl = e8 / 100, r = e8 % 100, w = r >> 2, c8 = r & 3;
            int tg = t0 - 4 + tl;
            int i8 = 32*ks + c8*8;
            uint4 packed = {0,0,0,0};
            if (tg >= 0 && tg < 300) {
                s8v raw = *(const s8v*)&gin[(size_t)((n*300 + tg)*25 + w)*64 + i8];
                float f[8];
                #pragma unroll
                for (int j = 0; j < 8; ++j)
                    f[j] = fmaxf(fmaf(bf2f((unsigned short)raw[j]), sbs[i8+j], sbs[64+i8+j]), 0.f);
                packed.x = cvt_pk(f[0], f[1]);
                packed.y = cvt_pk(f[2], f[3]);
                packed.z = cvt_pk(f[4], f[5]);
                packed.w = cvt_pk(f[6], f[7]);
            }
            *(uint4*)&pT[(tl*25 + w)*40 + c8*8] = packed;
        }
        __syncthreads();

        #pragma unroll
        for (int i = 0; i < 7; ++i) {
            int col = lr + 16*(ch*7 + i); if (col > 199) col = 199;
            #pragma unroll
            for (int dt = 0; dt < 9; ++dt) {
                bf16x8 b = *(const bf16x8*)&pT[(col + 25*dt)*40 + 8*lg];
                acc[i] = __builtin_amdgcn_mfma_f32_16x16x32_bf16(af[dt], b, acc[i], 0, 0, 0);
            }
        }
    }

    const int lim = min(200, (300 - t0)*25);
    float tbc[4];
    #pragma unroll
    for (int r = 0; r < 4; ++r) tbc[r] = tb[cbase + r];

    float sacc[4] = {0,0,0,0}, qacc[4] = {0,0,0,0};
    #pragma unroll
    for (int i = 0; i < 7; ++i) {
        int col = lr + 16*(ch*7 + i);
        if (col < lim) {
            #pragma unroll
            for (int r = 0; r < 4; ++r) {
                float v = acc[i][r] + tbc[r];
                sacc[r] += v; qacc[r] += v*v;
            }
        }
    }
    #pragma unroll
    for (int r = 0; r < 4; ++r) {
        float s = sacc[r], q = qacc[r];
        s += __shfl_xor(s, 1); s += __shfl_xor(s, 2);
        s += __shfl_xor(s, 4); s += __shfl_xor(s, 8);
        q += __shfl_xor(q, 1); q += __shfl_xor(q, 2);
        q += __shfl_xor(q, 4); q += __shfl_xor(q, 8);
        if (lr == 0) {
            float* dst = stats4 + (size_t)((n*38 + tt)*2 + ch)*128;
            dst[cbase + r] = s;
            dst[64 + cbase + r] = q;
        }
    }

    __syncthreads();
    unsigned short* hbuf = pT;   // [64][200] bf16
    #pragma unroll
    for (int i = 0; i < 7; ++i) {
        int col = lr + 16*(ch*7 + i);
        if (col < 200) {
            #pragma unroll
            for (int r = 0; r < 4; ++r)
                hbuf[(cbase + r)*200 + col] = f2bf(acc[i][r] + tbc[r]);
        }
    }
    __syncthreads();
    for (int e = tid; e < 3200; e += 512) {
        int row = e / 50, c4 = (e % 50)*4;
        if (c4 < lim) {
            s4v o = *(const s4v*)&hbuf[row*200 + c4];
            *(s4v*)&hout[((size_t)(n*64 + row)*300 + t0)*25 + c4] = o;
        }
    }
}

// ---------------------------------------------------------------------------
// k_out: out = relu(bn2(h) + x) f32
// ---------------------------------------------------------------------------
__global__ __launch_bounds__(256) void k_out(
    const unsigned short* __restrict__ h, const float* __restrict__ x,
    const float* __restrict__ sb, float* __restrict__ out)
{
    int i4 = blockIdx.x * 256 + threadIdx.x;
    if (i4 >= NELEM/4) return;
    int c = ((i4*4) / TV) & 63;
    float s2 = sb[128 + c], b2 = sb[192 + c];
    s4v hv = *(const s4v*)&h[i4*4];
    float4 xv = ((const float4*)x)[i4];
    float4 o;
    o.x = fmaxf(fmaf(bf2f((unsigned short)hv[0]), s2, b2) + xv.x, 0.f);
    o.y = fmaxf(fmaf(bf2f((unsigned short)hv[1]), s2, b2) + xv.y, 0.f);
    o.z = fmaxf(fmaf(bf2f((unsigned short)hv[2]), s2, b2) + xv.z, 0.f);
    o.w = fmaxf(fmaf(bf2f((unsigned short)hv[3]), s2, b2) + xv.w, 0.f);
    ((float4*)out)[i4] = o;
}

// ---------------------------------------------------------------------------
extern "C" void kernel_launch(void* const* d_in, const int* in_sizes, int n_in,
                              void* d_out, int out_size, void* d_ws, size_t ws_size,
                              hipStream_t stream)
{
    const float* x      = (const float*)d_in[0];
    const float* A      = (const float*)d_in[1];
    const float* B      = (const float*)d_in[2];
    const float* lamda  = (const float*)d_in[3];
    const float* conv_w = (const float*)d_in[4];
    const float* conv_b = (const float*)d_in[5];
    const float* bn1_g  = (const float*)d_in[6];
    const float* bn1_b  = (const float*)d_in[7];
    const float* tcn_w  = (const float*)d_in[8];
    const float* tcn_b  = (const float*)d_in[9];
    const float* bn2_g  = (const float*)d_in[10];
    const float* bn2_b  = (const float*)d_in[11];

    unsigned short* g = (unsigned short*)d_ws;          // NELEM bf16
    unsigned short* h = g + NELEM;                      // NELEM bf16
    float* stats3 = (float*)(h + NELEM);                // 960*128
    float* stats4 = stats3 + 960*128;                   // 2432*128
    float* sb     = stats4 + 2432*128;                  // 256
    unsigned short* w2b = (unsigned short*)(sb + 256);  // 20480
    unsigned short* twb = w2b + 20480;                  // 36864

    k_prep<<<32, 256, 0, stream>>>(conv_w, tcn_w, w2b, twb);
    k_gcn<<<dim3(30, N_), 256, 0, stream>>>(x, A, B, lamda, w2b, conv_b, g, stats3);
    k_fin<<<64, 256, 0, stream>>>(stats3, 960, sb, bn1_g, bn1_b);
    k_tcn<<<dim3(38, N_), 512, 0, stream>>>(g, sb, twb, tcn_b, h, stats4);
    k_fin<<<64, 256, 0, stream>>>(stats4, 2432, sb + 128, bn2_g, bn2_b);
    k_out<<<NELEM/4/256, 256, 0, stream>>>(h, x, sb, (float*)d_out);
}